// Round 7
// baseline (409.851 us; speedup 1.0000x reference)
//
#include <hip/hip_runtime.h>
#include <math.h>

typedef __attribute__((ext_vector_type(8))) short short8;
typedef __attribute__((ext_vector_type(4))) float f32x4;

#define N_SUBN   20000
#define E_EDGES  400000
#define R_REL    16
#define H_DIM    256
#define NBINS    (N_SUBN * R_REL)          // 320000 (dst,rel) buckets
#define SCAN_CHUNK 2048
#define NSCAN_BLOCKS ((NBINS + SCAN_CHUNK - 1) / SCAN_CHUNK)   // 157
#define NPAIRS   4096
#define TILE_N   32
#define NT_BLOCKS (N_SUBN / TILE_N)                            // 625 exact
#define D2       512
#define PLANE_B  (TILE_N * H_DIM * 2)      // 16384 bytes per bf16 plane

// ---- bf16 hi/lo split helpers (RNE) ----
__device__ __forceinline__ ushort f2bf(float x) {
    uint u = __float_as_uint(x);
    u += 0x7fffu + ((u >> 16) & 1u);
    return (ushort)(u >> 16);
}
__device__ __forceinline__ float bf2f(ushort h) {
    return __uint_as_float(((uint)h) << 16);
}

// ---------------- gather: h0 = emb[node_ids] ----------------
__global__ void k_gather(const float* __restrict__ emb, const int* __restrict__ nid,
                         float* __restrict__ h0) {
    int t = blockIdx.x * blockDim.x + threadIdx.x;   // 20000*64 float4 slots
    int node = t >> 6, c = (t & 63) << 2;
    if (node >= N_SUBN) return;
    const float4 s = *reinterpret_cast<const float4*>(emb + (size_t)nid[node] * H_DIM + c);
    *reinterpret_cast<float4*>(h0 + (size_t)node * H_DIM + c) = s;
}

// ---------------- CSR build over bin = dst*R + etype ----------------
__global__ void k_count(const int* __restrict__ dst, const int* __restrict__ ety,
                        int* __restrict__ cnt) {
    int e = blockIdx.x * 256 + threadIdx.x;
    if (e < E_EDGES) atomicAdd(&cnt[dst[e] * R_REL + ety[e]], 1);
}

__global__ void k_scan1(int* __restrict__ data, int* __restrict__ bs) {
    __shared__ int ts[256];
    int base = blockIdx.x * SCAN_CHUNK + threadIdx.x * 8;
    int v[8]; int s = 0;
#pragma unroll
    for (int j = 0; j < 8; j++) {
        int idx = base + j;
        v[j] = (idx < NBINS) ? data[idx] : 0;
        s += v[j];
    }
    ts[threadIdx.x] = s;
    __syncthreads();
    for (int off = 1; off < 256; off <<= 1) {
        int add = (threadIdx.x >= (unsigned)off) ? ts[threadIdx.x - off] : 0;
        __syncthreads();
        ts[threadIdx.x] += add;
        __syncthreads();
    }
    int excl = ts[threadIdx.x] - s;
    if (threadIdx.x == 255) bs[blockIdx.x] = ts[255];
    int run = excl;
#pragma unroll
    for (int j = 0; j < 8; j++) {
        int idx = base + j;
        if (idx < NBINS) data[idx] = run;
        run += v[j];
    }
}

__global__ void k_scan2(int* __restrict__ bs) {
    __shared__ int ls[NSCAN_BLOCKS];
    if (threadIdx.x < NSCAN_BLOCKS) ls[threadIdx.x] = bs[threadIdx.x];
    __syncthreads();
    if (threadIdx.x == 0) {
        int run = 0;
        for (int i = 0; i < NSCAN_BLOCKS; i++) { int t = ls[i]; ls[i] = run; run += t; }
    }
    __syncthreads();
    if (threadIdx.x < NSCAN_BLOCKS) bs[threadIdx.x] = ls[threadIdx.x];
}

__global__ void k_scan3(int* __restrict__ data, const int* __restrict__ bs) {
    int idx = blockIdx.x * 256 + threadIdx.x;
    if (idx < NBINS) data[idx] = data[idx] + bs[idx / SCAN_CHUNK];
}

// scatter increments segend in place: post-scatter segend[bin] = END of bin,
// beg(bin) = (bin==0) ? 0 : segend[bin-1]. Edge packed: (src<<17) | norm_q17.
__global__ void k_scatter(const int* __restrict__ src, const int* __restrict__ dst,
                          const int* __restrict__ ety, const float* __restrict__ nrm,
                          int* __restrict__ segend, uint* __restrict__ es) {
    int e = blockIdx.x * 256 + threadIdx.x;
    if (e >= E_EDGES) return;
    int bin = dst[e] * R_REL + ety[e];
    int pos = atomicAdd(&segend[bin], 1);
    float n = nrm[e];
    uint q = (uint)fminf(n * 131072.f + 0.5f, 131071.f);
    es[pos] = ((uint)src[e] << 17) | q;
}

// ---------------- combined pre-pack + segend zero (one dispatch) ----------------
__device__ __forceinline__ void prep_w_body(const float* __restrict__ w,
                                            ushort* __restrict__ wfrag, int t) {
    int lane = t & 63, f = t >> 6;
    int ot = f & 1, rb = f >> 1;              // rb = r*8+b
    int kbase = (lane >> 4) * 8, n = ot * 16 + (lane & 15);
    ushort hv[8], lv[8];
#pragma unroll
    for (int j = 0; j < 8; j++) {
        float x = w[(size_t)(rb * 32 + kbase + j) * 32 + n];
        ushort h = f2bf(x);
        ushort l = f2bf(x - bf2f(h));
        hv[j] = h; lv[j] = l;
    }
    *reinterpret_cast<short8*>(wfrag + ((size_t)(f * 2 + 0) * 64 + lane) * 8) =
        *reinterpret_cast<short8*>(hv);
    *reinterpret_cast<short8*>(wfrag + ((size_t)(f * 2 + 1) * 64 + lane) * 8) =
        *reinterpret_cast<short8*>(lv);
}

__device__ __forceinline__ void prep_lw_body(const float* __restrict__ lw,
                                             ushort* __restrict__ lwfrag, int t) {
    int lane = t & 63, g = t >> 6;
    int kt = g >> 4, ot = g & 15;
    int kbase = kt * 32 + (lane >> 4) * 8, n = ot * 16 + (lane & 15);
    ushort hv[8], lv[8];
#pragma unroll
    for (int j = 0; j < 8; j++) {
        float x = lw[(size_t)(kbase + j) * H_DIM + n];
        ushort h = f2bf(x);
        ushort l = f2bf(x - bf2f(h));
        hv[j] = h; lv[j] = l;
    }
    *reinterpret_cast<short8*>(lwfrag + ((size_t)(g * 2 + 0) * 64 + lane) * 8) =
        *reinterpret_cast<short8*>(hv);
    *reinterpret_cast<short8*>(lwfrag + ((size_t)(g * 2 + 1) * 64 + lane) * 8) =
        *reinterpret_cast<short8*>(lv);
}

__device__ __forceinline__ void prep_fc1_body(const float* __restrict__ w,
                                              ushort* __restrict__ wfrag, int t) {
    int lane = t & 63, g = t >> 6;
    int kt = g >> 5, ot = g & 31;
    int kbase = kt * 32 + (lane >> 4) * 8, n = ot * 16 + (lane & 15);
    ushort hv[8], lv[8];
#pragma unroll
    for (int j = 0; j < 8; j++) {
        float x = w[(size_t)(kbase + j) * D2 + n];
        ushort h = f2bf(x);
        ushort l = f2bf(x - bf2f(h));
        hv[j] = h; lv[j] = l;
    }
    *reinterpret_cast<short8*>(wfrag + ((size_t)(g * 2 + 0) * 64 + lane) * 8) =
        *reinterpret_cast<short8*>(hv);
    *reinterpret_cast<short8*>(wfrag + ((size_t)(g * 2 + 1) * 64 + lane) * 8) =
        *reinterpret_cast<short8*>(lv);
}

#define ZBLOCKS ((NBINS + 255) / 256)   // 1250

__global__ void k_prep_all(const float* __restrict__ w1, const float* __restrict__ w2,
                           const float* __restrict__ lw1, const float* __restrict__ lw2,
                           const float* __restrict__ fc1W,
                           ushort* __restrict__ wfrag1, ushort* __restrict__ wfrag2,
                           ushort* __restrict__ lwfrag1, ushort* __restrict__ lwfrag2,
                           ushort* __restrict__ fc1frag, int* __restrict__ segend) {
    int b = blockIdx.x, tid = threadIdx.x;
    if (b < 64)        prep_w_body(w1, wfrag1, b * 256 + tid);
    else if (b < 128)  prep_w_body(w2, wfrag2, (b - 64) * 256 + tid);
    else if (b < 160)  prep_lw_body(lw1, lwfrag1, (b - 128) * 256 + tid);
    else if (b < 192)  prep_lw_body(lw2, lwfrag2, (b - 160) * 256 + tid);
    else if (b < 320)  prep_fc1_body(fc1W, fc1frag, (b - 192) * 256 + tid);
    else {
        int i = (b - 320) * 256 + tid;
        if (i < NBINS) segend[i] = 0;
    }
}

// ---------------- fused RGCN-BDD layer (MFMA, bf16 hi/lo 3-term) ----------------
// block = 32 dst nodes, 512 threads = 8 waves. LDS double-buffered: per rel r,
// wave does {MFMA(r) from buf[r&1]; aggregate(r+1) into buf[r&1^1]; ONE barrier}.
// Waves finishing MFMA early start issuing agg loads while siblings compute.
// Aggregation: 4 concurrently-interleaved edge cursors per wave (4 nodes).
__global__ __launch_bounds__(512) void k_layer(
    const float* __restrict__ hin, const uint* __restrict__ es, const int* __restrict__ segend,
    const ushort* __restrict__ wfrag, const ushort* __restrict__ lwfrag,
    const float* __restrict__ bias, float* __restrict__ hout) {
    __shared__ __align__(16) ushort aggH[2][TILE_N * H_DIM];
    __shared__ __align__(16) ushort aggLo[2][TILE_N * H_DIM];
    __shared__ int lofs[TILE_N * R_REL + 1];    // lofs[j]=beg of local bin j; [j+1]=end
    char* cH = (char*)aggH;
    char* cL = (char*)aggLo;
    const int n0 = blockIdx.x * TILE_N;
    const int tid = threadIdx.x;
    const int lane = tid & 63, wv = tid >> 6;
    const int col = lane & 15, kg = lane >> 4;
    const short8* wf  = (const short8*)wfrag;
    const short8* lwf = (const short8*)lwfrag;
    const uint laneoff = (uint)(lane << 2);
    const int t0 = 4 * wv;

    {   // block-local offset table (coalesced, once)
        const int base = n0 * R_REL;
        for (int j = tid; j < TILE_N * R_REL + 1; j += 512) {
            int g = base + j - 1;
            lofs[j] = (g < 0) ? 0 : segend[g];
        }
    }

    f32x4 acc[2][2];
#pragma unroll
    for (int mt = 0; mt < 2; ++mt)
#pragma unroll
        for (int ot = 0; ot < 2; ++ot) acc[mt][ot] = (f32x4){0.f, 0.f, 0.f, 0.f};

    // aggregate relation rr into LDS buffer bb (registers -> swizzled bf16 hi/lo)
    auto aggregate = [&](int rr, int bb) {
        int e0 = lofs[(t0 + 0) * R_REL + rr], d0 = lofs[(t0 + 0) * R_REL + rr + 1];
        int e1 = lofs[(t0 + 1) * R_REL + rr], d1 = lofs[(t0 + 1) * R_REL + rr + 1];
        int e2 = lofs[(t0 + 2) * R_REL + rr], d2 = lofs[(t0 + 2) * R_REL + rr + 1];
        int e3 = lofs[(t0 + 3) * R_REL + rr], d3 = lofs[(t0 + 3) * R_REL + rr + 1];
        float4 a0 = make_float4(0.f, 0.f, 0.f, 0.f);
        float4 a1 = make_float4(0.f, 0.f, 0.f, 0.f);
        float4 a2 = make_float4(0.f, 0.f, 0.f, 0.f);
        float4 a3 = make_float4(0.f, 0.f, 0.f, 0.f);
        while ((e0 < d0) | (e1 < d1) | (e2 < d2) | (e3 < d3)) {
            bool g0 = e0 < d0, g1 = e1 < d1, g2 = e2 < d2, g3 = e3 < d3;
            uint p0 = 0, p1 = 0, p2 = 0, p3 = 0;
            if (g0) p0 = es[e0++];
            if (g1) p1 = es[e1++];
            if (g2) p2 = es[e2++];
            if (g3) p3 = es[e3++];
            if (g0) {
                const float4 x = *reinterpret_cast<const float4*>(
                    hin + (size_t)(p0 >> 17) * H_DIM + laneoff);
                float nm = (float)(p0 & 0x1FFFFu) * (1.f / 131072.f);
                a0.x = fmaf(x.x, nm, a0.x); a0.y = fmaf(x.y, nm, a0.y);
                a0.z = fmaf(x.z, nm, a0.z); a0.w = fmaf(x.w, nm, a0.w);
            }
            if (g1) {
                const float4 x = *reinterpret_cast<const float4*>(
                    hin + (size_t)(p1 >> 17) * H_DIM + laneoff);
                float nm = (float)(p1 & 0x1FFFFu) * (1.f / 131072.f);
                a1.x = fmaf(x.x, nm, a1.x); a1.y = fmaf(x.y, nm, a1.y);
                a1.z = fmaf(x.z, nm, a1.z); a1.w = fmaf(x.w, nm, a1.w);
            }
            if (g2) {
                const float4 x = *reinterpret_cast<const float4*>(
                    hin + (size_t)(p2 >> 17) * H_DIM + laneoff);
                float nm = (float)(p2 & 0x1FFFFu) * (1.f / 131072.f);
                a2.x = fmaf(x.x, nm, a2.x); a2.y = fmaf(x.y, nm, a2.y);
                a2.z = fmaf(x.z, nm, a2.z); a2.w = fmaf(x.w, nm, a2.w);
            }
            if (g3) {
                const float4 x = *reinterpret_cast<const float4*>(
                    hin + (size_t)(p3 >> 17) * H_DIM + laneoff);
                float nm = (float)(p3 & 0x1FFFFu) * (1.f / 131072.f);
                a3.x = fmaf(x.x, nm, a3.x); a3.y = fmaf(x.y, nm, a3.y);
                a3.z = fmaf(x.z, nm, a3.z); a3.w = fmaf(x.w, nm, a3.w);
            }
        }
        const uint bbase = (uint)bb * PLANE_B;
#pragma unroll
        for (int i = 0; i < 4; ++i) {
            float4 av = (i == 0) ? a0 : (i == 1) ? a1 : (i == 2) ? a2 : a3;
            int t = t0 + i;
            ushort h0 = f2bf(av.x), h1 = f2bf(av.y), h2 = f2bf(av.z), h3 = f2bf(av.w);
            uint2 ph = make_uint2((uint)h0 | ((uint)h1 << 16), (uint)h2 | ((uint)h3 << 16));
            uint2 pl = make_uint2(
                (uint)f2bf(av.x - bf2f(h0)) | ((uint)f2bf(av.y - bf2f(h1)) << 16),
                (uint)f2bf(av.z - bf2f(h2)) | ((uint)f2bf(av.w - bf2f(h3)) << 16));
            uint byte = bbase + (uint)(t * 512) +
                        ((((lane >> 1) ^ (t & 7)) << 4) | ((lane & 1) << 3));
            *(uint2*)(cH + byte) = ph;
            *(uint2*)(cL + byte) = pl;
        }
    };

    // stage own rows (self-loop operand) into buffer bb
    auto stage_self = [&](int bb) {
        const uint bbase = (uint)bb * PLANE_B;
#pragma unroll
        for (int i = 0; i < 4; ++i) {
            int t = t0 + i;
            const float4 xv = *reinterpret_cast<const float4*>(
                hin + (size_t)(n0 + t) * H_DIM + laneoff);
            ushort h0 = f2bf(xv.x), h1 = f2bf(xv.y), h2 = f2bf(xv.z), h3 = f2bf(xv.w);
            uint2 ph = make_uint2((uint)h0 | ((uint)h1 << 16), (uint)h2 | ((uint)h3 << 16));
            uint2 pl = make_uint2(
                (uint)f2bf(xv.x - bf2f(h0)) | ((uint)f2bf(xv.y - bf2f(h1)) << 16),
                (uint)f2bf(xv.z - bf2f(h2)) | ((uint)f2bf(xv.w - bf2f(h3)) << 16));
            uint byte = bbase + (uint)(t * 512) +
                        ((((lane >> 1) ^ (t & 7)) << 4) | ((lane & 1) << 3));
            *(uint2*)(cH + byte) = ph;
            *(uint2*)(cL + byte) = pl;
        }
    };

    __syncthreads();           // lofs ready
    aggregate(0, 0);           // prologue: rel 0 into buf0
    __syncthreads();

    for (int r = 0; r < R_REL; ++r) {
        const int cur = r & 1;
        const uint bbase = (uint)cur * PLANE_B;
        // ---- MFMA for rel r from buf[cur] ----
        __builtin_amdgcn_s_setprio(1);
#pragma unroll
        for (int ot = 0; ot < 2; ++ot) {
            int f = (r * 8 + wv) * 2 + ot;
            short8 Bh = wf[(f * 2 + 0) * 64 + lane];
            short8 Bl = wf[(f * 2 + 1) * 64 + lane];
#pragma unroll
            for (int mt = 0; mt < 2; ++mt) {
                int row = mt * 16 + col;
                uint ab = bbase + (uint)(row * 512) + ((uint)((wv * 4 + kg) ^ (row & 7)) << 4);
                short8 Ah = *(const short8*)(cH + ab);
                short8 Al = *(const short8*)(cL + ab);
                f32x4 a = acc[mt][ot];
                a = __builtin_amdgcn_mfma_f32_16x16x32_bf16(Ah, Bh, a, 0, 0, 0);
                a = __builtin_amdgcn_mfma_f32_16x16x32_bf16(Ah, Bl, a, 0, 0, 0);
                a = __builtin_amdgcn_mfma_f32_16x16x32_bf16(Al, Bh, a, 0, 0, 0);
                acc[mt][ot] = a;
            }
        }
        __builtin_amdgcn_s_setprio(0);
        // ---- produce next buffer: rel r+1 (or self rows at the end) ----
        if (r < R_REL - 1) aggregate(r + 1, cur ^ 1);
        else               stage_self(cur ^ 1);
        __syncthreads();
    }

    // ---- self-loop MFMA: K=256 sweep from buf[16&1 = 0] ----
    __builtin_amdgcn_s_setprio(1);
#pragma unroll
    for (int kt = 0; kt < 8; ++kt) {
#pragma unroll
        for (int ot = 0; ot < 2; ++ot) {
            int g = kt * 16 + 2 * wv + ot;
            short8 Bh = lwf[(g * 2 + 0) * 64 + lane];
            short8 Bl = lwf[(g * 2 + 1) * 64 + lane];
#pragma unroll
            for (int mt = 0; mt < 2; ++mt) {
                int row = mt * 16 + col;
                uint ab = (uint)(row * 512) + ((uint)((kt * 4 + kg) ^ (row & 7)) << 4);
                short8 Ah = *(const short8*)(cH + ab);
                short8 Al = *(const short8*)(cL + ab);
                f32x4 a = acc[mt][ot];
                a = __builtin_amdgcn_mfma_f32_16x16x32_bf16(Ah, Bh, a, 0, 0, 0);
                a = __builtin_amdgcn_mfma_f32_16x16x32_bf16(Ah, Bl, a, 0, 0, 0);
                a = __builtin_amdgcn_mfma_f32_16x16x32_bf16(Al, Bh, a, 0, 0, 0);
                acc[mt][ot] = a;
            }
        }
    }
    __builtin_amdgcn_s_setprio(0);

    // ---- epilogue: C/D layout col=lane&15, row=(lane>>4)*4+reg ----
#pragma unroll
    for (int mt = 0; mt < 2; ++mt) {
        int nbase = n0 + mt * 16 + kg * 4;
#pragma unroll
        for (int ot = 0; ot < 2; ++ot) {
            int o = 32 * wv + ot * 16 + col;
            float bo = bias[o];
#pragma unroll
            for (int rg = 0; rg < 4; ++rg)
                hout[(size_t)(nbase + rg) * H_DIM + o] = acc[mt][ot][rg] + bo;
        }
    }
}

// ---------------- fused concat + fc1(MFMA) + relu + fc2 + sigmoid ----------------
__global__ __launch_bounds__(512) void k_mlp(
    const float* __restrict__ h, const int* __restrict__ drugs, const int* __restrict__ targets,
    const ushort* __restrict__ fc1frag, const float* __restrict__ b1f,
    const float* __restrict__ W2, const float* __restrict__ b2f,
    float* __restrict__ outp) {
    __shared__ __align__(16) ushort xH[16 * D2];
    __shared__ __align__(16) ushort xL[16 * D2];
    __shared__ float red[16][8];
    char* cH = (char*)xH;
    char* cL = (char*)xL;
    const int tid = threadIdx.x;
    const int lane = tid & 63, wv = tid >> 6;
    const int col = lane & 15, kg = lane >> 4;
    const int p0 = blockIdx.x * 16;
    const short8* wf = (const short8*)fc1frag;

    {   // stage X = [h[drug] | h[target]] as bf16 hi/lo, swizzled
        int p = tid >> 5;
        int cc = (tid & 31) * 16;
        int di = drugs[p0 + p], ti = targets[p0 + p];
        const float* srcp = (cc < H_DIM) ? (h + (size_t)di * H_DIM + cc)
                                         : (h + (size_t)ti * H_DIM + (cc - H_DIM));
#pragma unroll
        for (int j = 0; j < 2; ++j) {
            float4 a = *reinterpret_cast<const float4*>(srcp + j * 8);
            float4 b = *reinterpret_cast<const float4*>(srcp + j * 8 + 4);
            float f[8] = {a.x, a.y, a.z, a.w, b.x, b.y, b.z, b.w};
            short8 hv, lv;
#pragma unroll
            for (int q = 0; q < 8; ++q) {
                ushort hh = f2bf(f[q]);
                hv[q] = (short)hh;
                lv[q] = (short)f2bf(f[q] - bf2f(hh));
            }
            uint chunk = (uint)((tid & 31) * 2 + j);
            uint byte = (uint)p * 1024 + ((chunk ^ (uint)(p & 7)) << 4);
            *(short8*)(cH + byte) = hv;
            *(short8*)(cL + byte) = lv;
        }
    }
    __syncthreads();

    f32x4 acc[4];
#pragma unroll
    for (int oi = 0; oi < 4; ++oi) acc[oi] = (f32x4){0.f, 0.f, 0.f, 0.f};

    for (int kt = 0; kt < 16; ++kt) {
        uint ab = (uint)col * 1024 + ((uint)((kt * 4 + kg) ^ (col & 7)) << 4);
        short8 Ah = *(const short8*)(cH + ab);
        short8 Al = *(const short8*)(cL + ab);
#pragma unroll
        for (int oi = 0; oi < 4; ++oi) {
            int g = kt * 32 + wv * 4 + oi;
            short8 Bh = wf[(g * 2 + 0) * 64 + lane];
            short8 Bl = wf[(g * 2 + 1) * 64 + lane];
            f32x4 a = acc[oi];
            a = __builtin_amdgcn_mfma_f32_16x16x32_bf16(Ah, Bh, a, 0, 0, 0);
            a = __builtin_amdgcn_mfma_f32_16x16x32_bf16(Ah, Bl, a, 0, 0, 0);
            a = __builtin_amdgcn_mfma_f32_16x16x32_bf16(Al, Bh, a, 0, 0, 0);
            a = __builtin_amdgcn_mfma_f32_16x16x32_bf16(Al, Bl, a, 0, 0, 0);
            acc[oi] = a;
        }
    }

    float val[4] = {0.f, 0.f, 0.f, 0.f};
#pragma unroll
    for (int oi = 0; oi < 4; ++oi) {
        int o = 64 * wv + oi * 16 + col;
        float b1o = b1f[o], w2o = W2[o];
#pragma unroll
        for (int rg = 0; rg < 4; ++rg) {
            float y = acc[oi][rg] + b1o;
            y = y > 0.f ? y : 0.f;
            val[rg] = fmaf(y, w2o, val[rg]);
        }
    }
#pragma unroll
    for (int rg = 0; rg < 4; ++rg) {
        float v = val[rg];
        v += __shfl_xor(v, 1, 64);
        v += __shfl_xor(v, 2, 64);
        v += __shfl_xor(v, 4, 64);
        v += __shfl_xor(v, 8, 64);
        val[rg] = v;
    }
    if (col == 0) {
#pragma unroll
        for (int rg = 0; rg < 4; ++rg) red[kg * 4 + rg][wv] = val[rg];
    }
    __syncthreads();
    if (tid < 16) {
        float s = 0.f;
#pragma unroll
        for (int w = 0; w < 8; w++) s += red[tid][w];
        s += b2f[0];
        outp[p0 + tid] = 1.f / (1.f + __expf(-s));
    }
}

extern "C" void kernel_launch(void* const* d_in, const int* in_sizes, int n_in,
                              void* d_out, int out_size, void* d_ws, size_t ws_size,
                              hipStream_t stream) {
    (void)in_sizes; (void)n_in; (void)out_size; (void)ws_size;
    const int*   drugs   = (const int*)d_in[0];
    const int*   targets = (const int*)d_in[1];
    const int*   nid     = (const int*)d_in[2];
    const int*   src     = (const int*)d_in[3];
    const int*   dst     = (const int*)d_in[4];
    const int*   ety     = (const int*)d_in[5];
    const float* nrm     = (const float*)d_in[6];
    const float* emb     = (const float*)d_in[7];
    const float* w1      = (const float*)d_in[8];
    const float* lw1     = (const float*)d_in[9];
    const float* b1      = (const float*)d_in[10];
    const float* w2      = (const float*)d_in[11];
    const float* lw2     = (const float*)d_in[12];
    const float* b2      = (const float*)d_in[13];
    const float* fc1W    = (const float*)d_in[14];
    const float* fc1b    = (const float*)d_in[15];
    const float* fc2W    = (const float*)d_in[16];
    const float* fc2b    = (const float*)d_in[17];
    float* outp = (float*)d_out;

    // ws layout — total 46,462,464 B (within proven budget).
    char* ws = (char*)d_ws;
    ushort* wfrag1  = (ushort*)(ws);                    //    524,288
    ushort* wfrag2  = (ushort*)(ws + 524288);           //    524,288
    ushort* lwfrag1 = (ushort*)(ws + 1048576);          //    262,144
    ushort* lwfrag2 = (ushort*)(ws + 1310720);          //    262,144
    ushort* fc1frag = (ushort*)(ws + 1572864);          //  1,048,576
    float*  hA      = (float*) (ws + 2621440);          // 20,480,000
    float*  hB      = (float*) (ws + 23101440);         // 20,480,000
    int*    segend  = (int*)   (ws + 43581440);         //  1,280,000
    int*    bs      = (int*)   (ws + 44861440);         //      1,024
    uint*   es      = (uint*)  (ws + 44862464);         //  1,600,000 -> end 46,462,464

    k_prep_all<<<320 + ZBLOCKS, 256, 0, stream>>>(w1, w2, lw1, lw2, fc1W,
                                                  wfrag1, wfrag2, lwfrag1, lwfrag2,
                                                  fc1frag, segend);
    k_gather <<<5000, 256, 0, stream>>>(emb, nid, hA);
    k_count  <<<(E_EDGES + 255) / 256, 256, 0, stream>>>(dst, ety, segend);
    k_scan1  <<<NSCAN_BLOCKS, 256, 0, stream>>>(segend, bs);
    k_scan2  <<<1, 256, 0, stream>>>(bs);
    k_scan3  <<<(NBINS + 255) / 256, 256, 0, stream>>>(segend, bs);
    k_scatter<<<(E_EDGES + 255) / 256, 256, 0, stream>>>(src, dst, ety, nrm, segend, es);
    k_layer  <<<NT_BLOCKS, 512, 0, stream>>>(hA, es, segend, wfrag1, lwfrag1, b1, hB);
    k_layer  <<<NT_BLOCKS, 512, 0, stream>>>(hB, es, segend, wfrag2, lwfrag2, b2, hA);
    k_mlp    <<<NPAIRS / 16, 512, 0, stream>>>(hA, drugs, targets, fc1frag, fc1b, fc2W, fc2b, outp);
}

// Round 8
// 381.560 us; speedup vs baseline: 1.0741x; 1.0741x over previous
//
#include <hip/hip_runtime.h>
#include <math.h>

typedef __attribute__((ext_vector_type(8))) short short8;
typedef __attribute__((ext_vector_type(4))) float f32x4;

#define N_SUBN   20000
#define E_EDGES  400000
#define R_REL    16
#define H_DIM    256
#define NBINS    (N_SUBN * R_REL)          // 320000 (dst,rel) buckets
#define SCAN_CHUNK 2048
#define NSCAN_BLOCKS ((NBINS + SCAN_CHUNK - 1) / SCAN_CHUNK)   // 157
#define NPAIRS   4096
#define TILE_N   32
#define NT_BLOCKS (N_SUBN / TILE_N)                            // 625 exact
#define D2       512

// ---- bf16 hi/lo split helpers (RNE) ----
__device__ __forceinline__ ushort f2bf(float x) {
    uint u = __float_as_uint(x);
    u += 0x7fffu + ((u >> 16) & 1u);
    return (ushort)(u >> 16);
}
__device__ __forceinline__ float bf2f(ushort h) {
    return __uint_as_float(((uint)h) << 16);
}

// ---------------- gather: h0 = emb[node_ids] ----------------
__global__ void k_gather(const float* __restrict__ emb, const int* __restrict__ nid,
                         float* __restrict__ h0) {
    int t = blockIdx.x * blockDim.x + threadIdx.x;   // 20000*64 float4 slots
    int node = t >> 6, c = (t & 63) << 2;
    if (node >= N_SUBN) return;
    const float4 s = *reinterpret_cast<const float4*>(emb + (size_t)nid[node] * H_DIM + c);
    *reinterpret_cast<float4*>(h0 + (size_t)node * H_DIM + c) = s;
}

// ---------------- CSR build over bin = dst*R + etype ----------------
__global__ void k_count(const int* __restrict__ dst, const int* __restrict__ ety,
                        int* __restrict__ cnt) {
    int e = blockIdx.x * 256 + threadIdx.x;
    if (e < E_EDGES) atomicAdd(&cnt[dst[e] * R_REL + ety[e]], 1);
}

__global__ void k_scan1(int* __restrict__ data, int* __restrict__ bs) {
    __shared__ int ts[256];
    int base = blockIdx.x * SCAN_CHUNK + threadIdx.x * 8;
    int v[8]; int s = 0;
#pragma unroll
    for (int j = 0; j < 8; j++) {
        int idx = base + j;
        v[j] = (idx < NBINS) ? data[idx] : 0;
        s += v[j];
    }
    ts[threadIdx.x] = s;
    __syncthreads();
    for (int off = 1; off < 256; off <<= 1) {
        int add = (threadIdx.x >= (unsigned)off) ? ts[threadIdx.x - off] : 0;
        __syncthreads();
        ts[threadIdx.x] += add;
        __syncthreads();
    }
    int excl = ts[threadIdx.x] - s;
    if (threadIdx.x == 255) bs[blockIdx.x] = ts[255];
    int run = excl;
#pragma unroll
    for (int j = 0; j < 8; j++) {
        int idx = base + j;
        if (idx < NBINS) data[idx] = run;
        run += v[j];
    }
}

__global__ void k_scan2(int* __restrict__ bs) {
    __shared__ int ls[NSCAN_BLOCKS];
    if (threadIdx.x < NSCAN_BLOCKS) ls[threadIdx.x] = bs[threadIdx.x];
    __syncthreads();
    if (threadIdx.x == 0) {
        int run = 0;
        for (int i = 0; i < NSCAN_BLOCKS; i++) { int t = ls[i]; ls[i] = run; run += t; }
    }
    __syncthreads();
    if (threadIdx.x < NSCAN_BLOCKS) bs[threadIdx.x] = ls[threadIdx.x];
}

__global__ void k_scan3(int* __restrict__ data, const int* __restrict__ bs) {
    int idx = blockIdx.x * 256 + threadIdx.x;
    if (idx < NBINS) data[idx] = data[idx] + bs[idx / SCAN_CHUNK];
}

// scatter increments segend in place: post-scatter segend[bin] = END of bin,
// beg(bin) = (bin==0) ? 0 : segend[bin-1]. Edge packed: (src<<17) | norm_q17.
__global__ void k_scatter(const int* __restrict__ src, const int* __restrict__ dst,
                          const int* __restrict__ ety, const float* __restrict__ nrm,
                          int* __restrict__ segend, uint* __restrict__ es) {
    int e = blockIdx.x * 256 + threadIdx.x;
    if (e >= E_EDGES) return;
    int bin = dst[e] * R_REL + ety[e];
    int pos = atomicAdd(&segend[bin], 1);
    float n = nrm[e];
    uint q = (uint)fminf(n * 131072.f + 0.5f, 131071.f);
    es[pos] = ((uint)src[e] << 17) | q;
}

// ---------------- combined pre-pack + segend zero (one dispatch) ----------------
__device__ __forceinline__ void prep_w_body(const float* __restrict__ w,
                                            ushort* __restrict__ wfrag, int t) {
    int lane = t & 63, f = t >> 6;
    int ot = f & 1, rb = f >> 1;              // rb = r*8+b
    int kbase = (lane >> 4) * 8, n = ot * 16 + (lane & 15);
    ushort hv[8], lv[8];
#pragma unroll
    for (int j = 0; j < 8; j++) {
        float x = w[(size_t)(rb * 32 + kbase + j) * 32 + n];
        ushort h = f2bf(x);
        ushort l = f2bf(x - bf2f(h));
        hv[j] = h; lv[j] = l;
    }
    *reinterpret_cast<short8*>(wfrag + ((size_t)(f * 2 + 0) * 64 + lane) * 8) =
        *reinterpret_cast<short8*>(hv);
    *reinterpret_cast<short8*>(wfrag + ((size_t)(f * 2 + 1) * 64 + lane) * 8) =
        *reinterpret_cast<short8*>(lv);
}

__device__ __forceinline__ void prep_lw_body(const float* __restrict__ lw,
                                             ushort* __restrict__ lwfrag, int t) {
    int lane = t & 63, g = t >> 6;
    int kt = g >> 4, ot = g & 15;
    int kbase = kt * 32 + (lane >> 4) * 8, n = ot * 16 + (lane & 15);
    ushort hv[8], lv[8];
#pragma unroll
    for (int j = 0; j < 8; j++) {
        float x = lw[(size_t)(kbase + j) * H_DIM + n];
        ushort h = f2bf(x);
        ushort l = f2bf(x - bf2f(h));
        hv[j] = h; lv[j] = l;
    }
    *reinterpret_cast<short8*>(lwfrag + ((size_t)(g * 2 + 0) * 64 + lane) * 8) =
        *reinterpret_cast<short8*>(hv);
    *reinterpret_cast<short8*>(lwfrag + ((size_t)(g * 2 + 1) * 64 + lane) * 8) =
        *reinterpret_cast<short8*>(lv);
}

__device__ __forceinline__ void prep_fc1_body(const float* __restrict__ w,
                                              ushort* __restrict__ wfrag, int t) {
    int lane = t & 63, g = t >> 6;
    int kt = g >> 5, ot = g & 31;
    int kbase = kt * 32 + (lane >> 4) * 8, n = ot * 16 + (lane & 15);
    ushort hv[8], lv[8];
#pragma unroll
    for (int j = 0; j < 8; j++) {
        float x = w[(size_t)(kbase + j) * D2 + n];
        ushort h = f2bf(x);
        ushort l = f2bf(x - bf2f(h));
        hv[j] = h; lv[j] = l;
    }
    *reinterpret_cast<short8*>(wfrag + ((size_t)(g * 2 + 0) * 64 + lane) * 8) =
        *reinterpret_cast<short8*>(hv);
    *reinterpret_cast<short8*>(wfrag + ((size_t)(g * 2 + 1) * 64 + lane) * 8) =
        *reinterpret_cast<short8*>(lv);
}

#define ZBLOCKS ((NBINS + 255) / 256)   // 1250

__global__ void k_prep_all(const float* __restrict__ w1, const float* __restrict__ w2,
                           const float* __restrict__ lw1, const float* __restrict__ lw2,
                           const float* __restrict__ fc1W,
                           ushort* __restrict__ wfrag1, ushort* __restrict__ wfrag2,
                           ushort* __restrict__ lwfrag1, ushort* __restrict__ lwfrag2,
                           ushort* __restrict__ fc1frag, int* __restrict__ segend) {
    int b = blockIdx.x, tid = threadIdx.x;
    if (b < 64)        prep_w_body(w1, wfrag1, b * 256 + tid);
    else if (b < 128)  prep_w_body(w2, wfrag2, (b - 64) * 256 + tid);
    else if (b < 160)  prep_lw_body(lw1, lwfrag1, (b - 128) * 256 + tid);
    else if (b < 192)  prep_lw_body(lw2, lwfrag2, (b - 160) * 256 + tid);
    else if (b < 320)  prep_fc1_body(fc1W, fc1frag, (b - 192) * 256 + tid);
    else {
        int i = (b - 320) * 256 + tid;
        if (i < NBINS) segend[i] = 0;
    }
}

// ---------------- fused RGCN-BDD layer (MFMA, bf16 hi/lo 3-term) ----------------
// block = 32 dst nodes, 512 threads = 8 waves (round-6 structure: single buffer,
// 2 barriers/rel). NEW: cooperative edge-word fetch — per relation, lane l loads
// slot (l&15) of bin (l>>4) in ONE coalesced es read; edge words then distributed
// by __shfl, so the per-edge chain is only the h-row load (4 independent chains).
// deg>16 bins (P~1e-9) handled by a serial cleanup loop.
__global__ __launch_bounds__(512) void k_layer(
    const float* __restrict__ hin, const uint* __restrict__ es, const int* __restrict__ segend,
    const ushort* __restrict__ wfrag, const ushort* __restrict__ lwfrag,
    const float* __restrict__ bias, float* __restrict__ hout) {
    __shared__ __align__(16) ushort aggH[TILE_N * H_DIM];
    __shared__ __align__(16) ushort aggLo[TILE_N * H_DIM];
    __shared__ int lofs[TILE_N * R_REL + 1];    // lofs[j]=beg of local bin j; [j+1]=end
    char* cH = (char*)aggH;
    char* cL = (char*)aggLo;
    const int n0 = blockIdx.x * TILE_N;
    const int tid = threadIdx.x;
    const int lane = tid & 63, wv = tid >> 6;
    const int col = lane & 15, kg = lane >> 4;
    const short8* wf  = (const short8*)wfrag;
    const short8* lwf = (const short8*)lwfrag;
    const uint laneoff = (uint)(lane << 2);
    const int t0 = 4 * wv;
    const int myb = lane >> 4, mys = lane & 15;   // cooperative-fetch role

    {   // block-local offset table (coalesced, once)
        const int base = n0 * R_REL;
        for (int j = tid; j < TILE_N * R_REL + 1; j += 512) {
            int g = base + j - 1;
            lofs[j] = (g < 0) ? 0 : segend[g];
        }
    }

    f32x4 acc[2][2];
#pragma unroll
    for (int mt = 0; mt < 2; ++mt)
#pragma unroll
        for (int ot = 0; ot < 2; ++ot) acc[mt][ot] = (f32x4){0.f, 0.f, 0.f, 0.f};

    for (int r = 0; r < R_REL; ++r) {
        __syncthreads();   // lofs ready (r=0) / previous MFMA reads done
        // ---- bin bounds for this wave's 4 nodes ----
        int beg0 = lofs[(t0 + 0) * R_REL + r], end0 = lofs[(t0 + 0) * R_REL + r + 1];
        int beg1 = lofs[(t0 + 1) * R_REL + r], end1 = lofs[(t0 + 1) * R_REL + r + 1];
        int beg2 = lofs[(t0 + 2) * R_REL + r], end2 = lofs[(t0 + 2) * R_REL + r + 1];
        int beg3 = lofs[(t0 + 3) * R_REL + r], end3 = lofs[(t0 + 3) * R_REL + r + 1];
        // ---- cooperative es fetch: one coalesced load covers 16 slots x 4 bins ----
        int mybeg = (myb == 0) ? beg0 : (myb == 1) ? beg1 : (myb == 2) ? beg2 : beg3;
        int pos = mybeg + mys;
        uint pv = es[pos < E_EDGES ? pos : (E_EDGES - 1)];
        // limits for the register-resident chunk
        int l0 = min(end0, beg0 + 16), l1 = min(end1, beg1 + 16);
        int l2 = min(end2, beg2 + 16), l3 = min(end3, beg3 + 16);
        int c0 = beg0, c1 = beg1, c2 = beg2, c3 = beg3;
        float4 a0 = make_float4(0.f, 0.f, 0.f, 0.f);
        float4 a1 = make_float4(0.f, 0.f, 0.f, 0.f);
        float4 a2 = make_float4(0.f, 0.f, 0.f, 0.f);
        float4 a3 = make_float4(0.f, 0.f, 0.f, 0.f);
        while ((c0 < l0) | (c1 < l1) | (c2 < l2) | (c3 < l3)) {
            bool g0 = c0 < l0, g1 = c1 < l1, g2 = c2 < l2, g3 = c3 < l3;
            uint p0 = 0, p1 = 0, p2 = 0, p3 = 0;
            if (g0) p0 = __shfl(pv, c0 - beg0, 64);
            if (g1) p1 = __shfl(pv, 16 + (c1 - beg1), 64);
            if (g2) p2 = __shfl(pv, 32 + (c2 - beg2), 64);
            if (g3) p3 = __shfl(pv, 48 + (c3 - beg3), 64);
            if (g0) {
                const float4 x = *reinterpret_cast<const float4*>(
                    hin + (size_t)(p0 >> 17) * H_DIM + laneoff);
                float nm = (float)(p0 & 0x1FFFFu) * (1.f / 131072.f);
                a0.x = fmaf(x.x, nm, a0.x); a0.y = fmaf(x.y, nm, a0.y);
                a0.z = fmaf(x.z, nm, a0.z); a0.w = fmaf(x.w, nm, a0.w);
                ++c0;
            }
            if (g1) {
                const float4 x = *reinterpret_cast<const float4*>(
                    hin + (size_t)(p1 >> 17) * H_DIM + laneoff);
                float nm = (float)(p1 & 0x1FFFFu) * (1.f / 131072.f);
                a1.x = fmaf(x.x, nm, a1.x); a1.y = fmaf(x.y, nm, a1.y);
                a1.z = fmaf(x.z, nm, a1.z); a1.w = fmaf(x.w, nm, a1.w);
                ++c1;
            }
            if (g2) {
                const float4 x = *reinterpret_cast<const float4*>(
                    hin + (size_t)(p2 >> 17) * H_DIM + laneoff);
                float nm = (float)(p2 & 0x1FFFFu) * (1.f / 131072.f);
                a2.x = fmaf(x.x, nm, a2.x); a2.y = fmaf(x.y, nm, a2.y);
                a2.z = fmaf(x.z, nm, a2.z); a2.w = fmaf(x.w, nm, a2.w);
                ++c2;
            }
            if (g3) {
                const float4 x = *reinterpret_cast<const float4*>(
                    hin + (size_t)(p3 >> 17) * H_DIM + laneoff);
                float nm = (float)(p3 & 0x1FFFFu) * (1.f / 131072.f);
                a3.x = fmaf(x.x, nm, a3.x); a3.y = fmaf(x.y, nm, a3.y);
                a3.z = fmaf(x.z, nm, a3.z); a3.w = fmaf(x.w, nm, a3.w);
                ++c3;
            }
        }
        // ---- rare cleanup for deg>16 bins (serial, ~never executes) ----
        while (c0 < end0) {
            uint p = es[c0++];
            const float4 x = *reinterpret_cast<const float4*>(
                hin + (size_t)(p >> 17) * H_DIM + laneoff);
            float nm = (float)(p & 0x1FFFFu) * (1.f / 131072.f);
            a0.x = fmaf(x.x, nm, a0.x); a0.y = fmaf(x.y, nm, a0.y);
            a0.z = fmaf(x.z, nm, a0.z); a0.w = fmaf(x.w, nm, a0.w);
        }
        while (c1 < end1) {
            uint p = es[c1++];
            const float4 x = *reinterpret_cast<const float4*>(
                hin + (size_t)(p >> 17) * H_DIM + laneoff);
            float nm = (float)(p & 0x1FFFFu) * (1.f / 131072.f);
            a1.x = fmaf(x.x, nm, a1.x); a1.y = fmaf(x.y, nm, a1.y);
            a1.z = fmaf(x.z, nm, a1.z); a1.w = fmaf(x.w, nm, a1.w);
        }
        while (c2 < end2) {
            uint p = es[c2++];
            const float4 x = *reinterpret_cast<const float4*>(
                hin + (size_t)(p >> 17) * H_DIM + laneoff);
            float nm = (float)(p & 0x1FFFFu) * (1.f / 131072.f);
            a2.x = fmaf(x.x, nm, a2.x); a2.y = fmaf(x.y, nm, a2.y);
            a2.z = fmaf(x.z, nm, a2.z); a2.w = fmaf(x.w, nm, a2.w);
        }
        while (c3 < end3) {
            uint p = es[c3++];
            const float4 x = *reinterpret_cast<const float4*>(
                hin + (size_t)(p >> 17) * H_DIM + laneoff);
            float nm = (float)(p & 0x1FFFFu) * (1.f / 131072.f);
            a3.x = fmaf(x.x, nm, a3.x); a3.y = fmaf(x.y, nm, a3.y);
            a3.z = fmaf(x.z, nm, a3.z); a3.w = fmaf(x.w, nm, a3.w);
        }
        // ---- split + store to swizzled LDS planes ----
#pragma unroll
        for (int i = 0; i < 4; ++i) {
            float4 av = (i == 0) ? a0 : (i == 1) ? a1 : (i == 2) ? a2 : a3;
            int t = t0 + i;
            ushort h0 = f2bf(av.x), h1 = f2bf(av.y), h2 = f2bf(av.z), h3 = f2bf(av.w);
            uint2 ph = make_uint2((uint)h0 | ((uint)h1 << 16), (uint)h2 | ((uint)h3 << 16));
            uint2 pl = make_uint2(
                (uint)f2bf(av.x - bf2f(h0)) | ((uint)f2bf(av.y - bf2f(h1)) << 16),
                (uint)f2bf(av.z - bf2f(h2)) | ((uint)f2bf(av.w - bf2f(h3)) << 16));
            uint byte = (uint)(t * 512) + ((((lane >> 1) ^ (t & 7)) << 4) | ((lane & 1) << 3));
            *(uint2*)(cH + byte) = ph;
            *(uint2*)(cL + byte) = pl;
        }
        __syncthreads();
        // ---- transform: wave wv owns b-block wv ----
#pragma unroll
        for (int ot = 0; ot < 2; ++ot) {
            int f = (r * 8 + wv) * 2 + ot;
            short8 Bh = wf[(f * 2 + 0) * 64 + lane];
            short8 Bl = wf[(f * 2 + 1) * 64 + lane];
#pragma unroll
            for (int mt = 0; mt < 2; ++mt) {
                int row = mt * 16 + col;
                uint ab = (uint)(row * 512) + ((uint)((wv * 4 + kg) ^ (row & 7)) << 4);
                short8 Ah = *(const short8*)(cH + ab);
                short8 Al = *(const short8*)(cL + ab);
                f32x4 a = acc[mt][ot];
                a = __builtin_amdgcn_mfma_f32_16x16x32_bf16(Ah, Bh, a, 0, 0, 0);
                a = __builtin_amdgcn_mfma_f32_16x16x32_bf16(Ah, Bl, a, 0, 0, 0);
                a = __builtin_amdgcn_mfma_f32_16x16x32_bf16(Al, Bh, a, 0, 0, 0);
                acc[mt][ot] = a;
            }
        }
    }

    // ---- self-loop: restage h tile as hi/lo, K=256 MFMA sweep ----
    __syncthreads();
#pragma unroll
    for (int i = 0; i < 4; ++i) {
        int t = t0 + i;
        const float4 xv = *reinterpret_cast<const float4*>(
            hin + (size_t)(n0 + t) * H_DIM + laneoff);
        ushort h0 = f2bf(xv.x), h1 = f2bf(xv.y), h2 = f2bf(xv.z), h3 = f2bf(xv.w);
        uint2 ph = make_uint2((uint)h0 | ((uint)h1 << 16), (uint)h2 | ((uint)h3 << 16));
        uint2 pl = make_uint2(
            (uint)f2bf(xv.x - bf2f(h0)) | ((uint)f2bf(xv.y - bf2f(h1)) << 16),
            (uint)f2bf(xv.z - bf2f(h2)) | ((uint)f2bf(xv.w - bf2f(h3)) << 16));
        uint byte = (uint)(t * 512) + ((((lane >> 1) ^ (t & 7)) << 4) | ((lane & 1) << 3));
        *(uint2*)(cH + byte) = ph;
        *(uint2*)(cL + byte) = pl;
    }
    __syncthreads();
#pragma unroll
    for (int kt = 0; kt < 8; ++kt) {
#pragma unroll
        for (int ot = 0; ot < 2; ++ot) {
            int g = kt * 16 + 2 * wv + ot;
            short8 Bh = lwf[(g * 2 + 0) * 64 + lane];
            short8 Bl = lwf[(g * 2 + 1) * 64 + lane];
#pragma unroll
            for (int mt = 0; mt < 2; ++mt) {
                int row = mt * 16 + col;
                uint ab = (uint)(row * 512) + ((uint)((kt * 4 + kg) ^ (row & 7)) << 4);
                short8 Ah = *(const short8*)(cH + ab);
                short8 Al = *(const short8*)(cL + ab);
                f32x4 a = acc[mt][ot];
                a = __builtin_amdgcn_mfma_f32_16x16x32_bf16(Ah, Bh, a, 0, 0, 0);
                a = __builtin_amdgcn_mfma_f32_16x16x32_bf16(Ah, Bl, a, 0, 0, 0);
                a = __builtin_amdgcn_mfma_f32_16x16x32_bf16(Al, Bh, a, 0, 0, 0);
                acc[mt][ot] = a;
            }
        }
    }

    // ---- epilogue: C/D layout col=lane&15, row=(lane>>4)*4+reg ----
#pragma unroll
    for (int mt = 0; mt < 2; ++mt) {
        int nbase = n0 + mt * 16 + kg * 4;
#pragma unroll
        for (int ot = 0; ot < 2; ++ot) {
            int o = 32 * wv + ot * 16 + col;
            float bo = bias[o];
#pragma unroll
            for (int rg = 0; rg < 4; ++rg)
                hout[(size_t)(nbase + rg) * H_DIM + o] = acc[mt][ot][rg] + bo;
        }
    }
}

// ---------------- fused concat + fc1(MFMA) + relu + fc2 + sigmoid ----------------
__global__ __launch_bounds__(512) void k_mlp(
    const float* __restrict__ h, const int* __restrict__ drugs, const int* __restrict__ targets,
    const ushort* __restrict__ fc1frag, const float* __restrict__ b1f,
    const float* __restrict__ W2, const float* __restrict__ b2f,
    float* __restrict__ outp) {
    __shared__ __align__(16) ushort xH[16 * D2];
    __shared__ __align__(16) ushort xL[16 * D2];
    __shared__ float red[16][8];
    char* cH = (char*)xH;
    char* cL = (char*)xL;
    const int tid = threadIdx.x;
    const int lane = tid & 63, wv = tid >> 6;
    const int col = lane & 15, kg = lane >> 4;
    const int p0 = blockIdx.x * 16;
    const short8* wf = (const short8*)fc1frag;

    {   // stage X = [h[drug] | h[target]] as bf16 hi/lo, swizzled
        int p = tid >> 5;
        int cc = (tid & 31) * 16;
        int di = drugs[p0 + p], ti = targets[p0 + p];
        const float* srcp = (cc < H_DIM) ? (h + (size_t)di * H_DIM + cc)
                                         : (h + (size_t)ti * H_DIM + (cc - H_DIM));
#pragma unroll
        for (int j = 0; j < 2; ++j) {
            float4 a = *reinterpret_cast<const float4*>(srcp + j * 8);
            float4 b = *reinterpret_cast<const float4*>(srcp + j * 8 + 4);
            float f[8] = {a.x, a.y, a.z, a.w, b.x, b.y, b.z, b.w};
            short8 hv, lv;
#pragma unroll
            for (int q = 0; q < 8; ++q) {
                ushort hh = f2bf(f[q]);
                hv[q] = (short)hh;
                lv[q] = (short)f2bf(f[q] - bf2f(hh));
            }
            uint chunk = (uint)((tid & 31) * 2 + j);
            uint byte = (uint)p * 1024 + ((chunk ^ (uint)(p & 7)) << 4);
            *(short8*)(cH + byte) = hv;
            *(short8*)(cL + byte) = lv;
        }
    }
    __syncthreads();

    f32x4 acc[4];
#pragma unroll
    for (int oi = 0; oi < 4; ++oi) acc[oi] = (f32x4){0.f, 0.f, 0.f, 0.f};

    for (int kt = 0; kt < 16; ++kt) {
        uint ab = (uint)col * 1024 + ((uint)((kt * 4 + kg) ^ (col & 7)) << 4);
        short8 Ah = *(const short8*)(cH + ab);
        short8 Al = *(const short8*)(cL + ab);
#pragma unroll
        for (int oi = 0; oi < 4; ++oi) {
            int g = kt * 32 + wv * 4 + oi;
            short8 Bh = wf[(g * 2 + 0) * 64 + lane];
            short8 Bl = wf[(g * 2 + 1) * 64 + lane];
            f32x4 a = acc[oi];
            a = __builtin_amdgcn_mfma_f32_16x16x32_bf16(Ah, Bh, a, 0, 0, 0);
            a = __builtin_amdgcn_mfma_f32_16x16x32_bf16(Ah, Bl, a, 0, 0, 0);
            a = __builtin_amdgcn_mfma_f32_16x16x32_bf16(Al, Bh, a, 0, 0, 0);
            a = __builtin_amdgcn_mfma_f32_16x16x32_bf16(Al, Bl, a, 0, 0, 0);
            acc[oi] = a;
        }
    }

    float val[4] = {0.f, 0.f, 0.f, 0.f};
#pragma unroll
    for (int oi = 0; oi < 4; ++oi) {
        int o = 64 * wv + oi * 16 + col;
        float b1o = b1f[o], w2o = W2[o];
#pragma unroll
        for (int rg = 0; rg < 4; ++rg) {
            float y = acc[oi][rg] + b1o;
            y = y > 0.f ? y : 0.f;
            val[rg] = fmaf(y, w2o, val[rg]);
        }
    }
#pragma unroll
    for (int rg = 0; rg < 4; ++rg) {
        float v = val[rg];
        v += __shfl_xor(v, 1, 64);
        v += __shfl_xor(v, 2, 64);
        v += __shfl_xor(v, 4, 64);
        v += __shfl_xor(v, 8, 64);
        val[rg] = v;
    }
    if (col == 0) {
#pragma unroll
        for (int rg = 0; rg < 4; ++rg) red[kg * 4 + rg][wv] = val[rg];
    }
    __syncthreads();
    if (tid < 16) {
        float s = 0.f;
#pragma unroll
        for (int w = 0; w < 8; w++) s += red[tid][w];
        s += b2f[0];
        outp[p0 + tid] = 1.f / (1.f + __expf(-s));
    }
}

extern "C" void kernel_launch(void* const* d_in, const int* in_sizes, int n_in,
                              void* d_out, int out_size, void* d_ws, size_t ws_size,
                              hipStream_t stream) {
    (void)in_sizes; (void)n_in; (void)out_size; (void)ws_size;
    const int*   drugs   = (const int*)d_in[0];
    const int*   targets = (const int*)d_in[1];
    const int*   nid     = (const int*)d_in[2];
    const int*   src     = (const int*)d_in[3];
    const int*   dst     = (const int*)d_in[4];
    const int*   ety     = (const int*)d_in[5];
    const float* nrm     = (const float*)d_in[6];
    const float* emb     = (const float*)d_in[7];
    const float* w1      = (const float*)d_in[8];
    const float* lw1     = (const float*)d_in[9];
    const float* b1      = (const float*)d_in[10];
    const float* w2      = (const float*)d_in[11];
    const float* lw2     = (const float*)d_in[12];
    const float* b2      = (const float*)d_in[13];
    const float* fc1W    = (const float*)d_in[14];
    const float* fc1b    = (const float*)d_in[15];
    const float* fc2W    = (const float*)d_in[16];
    const float* fc2b    = (const float*)d_in[17];
    float* outp = (float*)d_out;

    // ws layout — total 46,462,464 B (within proven budget).
    char* ws = (char*)d_ws;
    ushort* wfrag1  = (ushort*)(ws);                    //    524,288
    ushort* wfrag2  = (ushort*)(ws + 524288);           //    524,288
    ushort* lwfrag1 = (ushort*)(ws + 1048576);          //    262,144
    ushort* lwfrag2 = (ushort*)(ws + 1310720);          //    262,144
    ushort* fc1frag = (ushort*)(ws + 1572864);          //  1,048,576
    float*  hA      = (float*) (ws + 2621440);          // 20,480,000
    float*  hB      = (float*) (ws + 23101440);         // 20,480,000
    int*    segend  = (int*)   (ws + 43581440);         //  1,280,000
    int*    bs      = (int*)   (ws + 44861440);         //      1,024
    uint*   es      = (uint*)  (ws + 44862464);         //  1,600,000 -> end 46,462,464

    k_prep_all<<<320 + ZBLOCKS, 256, 0, stream>>>(w1, w2, lw1, lw2, fc1W,
                                                  wfrag1, wfrag2, lwfrag1, lwfrag2,
                                                  fc1frag, segend);
    k_gather <<<5000, 256, 0, stream>>>(emb, nid, hA);
    k_count  <<<(E_EDGES + 255) / 256, 256, 0, stream>>>(dst, ety, segend);
    k_scan1  <<<NSCAN_BLOCKS, 256, 0, stream>>>(segend, bs);
    k_scan2  <<<1, 256, 0, stream>>>(bs);
    k_scan3  <<<(NBINS + 255) / 256, 256, 0, stream>>>(segend, bs);
    k_scatter<<<(E_EDGES + 255) / 256, 256, 0, stream>>>(src, dst, ety, nrm, segend, es);
    k_layer  <<<NT_BLOCKS, 512, 0, stream>>>(hA, es, segend, wfrag1, lwfrag1, b1, hB);
    k_layer  <<<NT_BLOCKS, 512, 0, stream>>>(hB, es, segend, wfrag2, lwfrag2, b2, hA);
    k_mlp    <<<NPAIRS / 16, 512, 0, stream>>>(hA, drugs, targets, fc1frag, fc1b, fc2W, fc2b, outp);
}

// Round 9
// 309.009 us; speedup vs baseline: 1.3263x; 1.2348x over previous
//
#include <hip/hip_runtime.h>
#include <math.h>

typedef __attribute__((ext_vector_type(8))) short short8;
typedef __attribute__((ext_vector_type(4))) float f32x4;

#define N_SUBN   20000
#define E_EDGES  400000
#define R_REL    16
#define H_DIM    256
#define NBINS    (N_SUBN * R_REL)          // 320000 (dst,rel) buckets
#define SCAN_CHUNK 2048
#define NSCAN_BLOCKS ((NBINS + SCAN_CHUNK - 1) / SCAN_CHUNK)   // 157
#define NPAIRS   4096
#define TILE_N   16
#define NT_BLOCKS (N_SUBN / TILE_N)                            // 1250 exact
#define D2       512
#define PLANE_B  (TILE_N * H_DIM * 2)      // 8192 bytes per bf16 plane per buffer

// ---- bf16 hi/lo split helpers (RNE) ----
__device__ __forceinline__ ushort f2bf(float x) {
    uint u = __float_as_uint(x);
    u += 0x7fffu + ((u >> 16) & 1u);
    return (ushort)(u >> 16);
}
__device__ __forceinline__ float bf2f(ushort h) {
    return __uint_as_float(((uint)h) << 16);
}

// ---------------- gather: h0 = emb[node_ids] ----------------
__global__ void k_gather(const float* __restrict__ emb, const int* __restrict__ nid,
                         float* __restrict__ h0) {
    int t = blockIdx.x * blockDim.x + threadIdx.x;   // 20000*64 float4 slots
    int node = t >> 6, c = (t & 63) << 2;
    if (node >= N_SUBN) return;
    const float4 s = *reinterpret_cast<const float4*>(emb + (size_t)nid[node] * H_DIM + c);
    *reinterpret_cast<float4*>(h0 + (size_t)node * H_DIM + c) = s;
}

// ---------------- CSR build over bin = dst*R + etype ----------------
__global__ void k_count(const int* __restrict__ dst, const int* __restrict__ ety,
                        int* __restrict__ cnt) {
    int e = blockIdx.x * 256 + threadIdx.x;
    if (e < E_EDGES) atomicAdd(&cnt[dst[e] * R_REL + ety[e]], 1);
}

__global__ void k_scan1(int* __restrict__ data, int* __restrict__ bs) {
    __shared__ int ts[256];
    int base = blockIdx.x * SCAN_CHUNK + threadIdx.x * 8;
    int v[8]; int s = 0;
#pragma unroll
    for (int j = 0; j < 8; j++) {
        int idx = base + j;
        v[j] = (idx < NBINS) ? data[idx] : 0;
        s += v[j];
    }
    ts[threadIdx.x] = s;
    __syncthreads();
    for (int off = 1; off < 256; off <<= 1) {
        int add = (threadIdx.x >= (unsigned)off) ? ts[threadIdx.x - off] : 0;
        __syncthreads();
        ts[threadIdx.x] += add;
        __syncthreads();
    }
    int excl = ts[threadIdx.x] - s;
    if (threadIdx.x == 255) bs[blockIdx.x] = ts[255];
    int run = excl;
#pragma unroll
    for (int j = 0; j < 8; j++) {
        int idx = base + j;
        if (idx < NBINS) data[idx] = run;
        run += v[j];
    }
}

__global__ void k_scan2(int* __restrict__ bs) {
    __shared__ int ls[NSCAN_BLOCKS];
    if (threadIdx.x < NSCAN_BLOCKS) ls[threadIdx.x] = bs[threadIdx.x];
    __syncthreads();
    if (threadIdx.x == 0) {
        int run = 0;
        for (int i = 0; i < NSCAN_BLOCKS; i++) { int t = ls[i]; ls[i] = run; run += t; }
    }
    __syncthreads();
    if (threadIdx.x < NSCAN_BLOCKS) bs[threadIdx.x] = ls[threadIdx.x];
}

__global__ void k_scan3(int* __restrict__ data, const int* __restrict__ bs) {
    int idx = blockIdx.x * 256 + threadIdx.x;
    if (idx < NBINS) data[idx] = data[idx] + bs[idx / SCAN_CHUNK];
}

// scatter increments segend in place: post-scatter segend[bin] = END of bin,
// beg(bin) = (bin==0) ? 0 : segend[bin-1]. Edge packed: (src<<17) | norm_q17.
__global__ void k_scatter(const int* __restrict__ src, const int* __restrict__ dst,
                          const int* __restrict__ ety, const float* __restrict__ nrm,
                          int* __restrict__ segend, uint* __restrict__ es) {
    int e = blockIdx.x * 256 + threadIdx.x;
    if (e >= E_EDGES) return;
    int bin = dst[e] * R_REL + ety[e];
    int pos = atomicAdd(&segend[bin], 1);
    float n = nrm[e];
    uint q = (uint)fminf(n * 131072.f + 0.5f, 131071.f);
    es[pos] = ((uint)src[e] << 17) | q;
}

// ---------------- combined pre-pack + segend zero (one dispatch) ----------------
__device__ __forceinline__ void prep_w_body(const float* __restrict__ w,
                                            ushort* __restrict__ wfrag, int t) {
    int lane = t & 63, f = t >> 6;
    int ot = f & 1, rb = f >> 1;              // rb = r*8+b
    int kbase = (lane >> 4) * 8, n = ot * 16 + (lane & 15);
    ushort hv[8], lv[8];
#pragma unroll
    for (int j = 0; j < 8; j++) {
        float x = w[(size_t)(rb * 32 + kbase + j) * 32 + n];
        ushort h = f2bf(x);
        ushort l = f2bf(x - bf2f(h));
        hv[j] = h; lv[j] = l;
    }
    *reinterpret_cast<short8*>(wfrag + ((size_t)(f * 2 + 0) * 64 + lane) * 8) =
        *reinterpret_cast<short8*>(hv);
    *reinterpret_cast<short8*>(wfrag + ((size_t)(f * 2 + 1) * 64 + lane) * 8) =
        *reinterpret_cast<short8*>(lv);
}

__device__ __forceinline__ void prep_lw_body(const float* __restrict__ lw,
                                             ushort* __restrict__ lwfrag, int t) {
    int lane = t & 63, g = t >> 6;
    int kt = g >> 4, ot = g & 15;
    int kbase = kt * 32 + (lane >> 4) * 8, n = ot * 16 + (lane & 15);
    ushort hv[8], lv[8];
#pragma unroll
    for (int j = 0; j < 8; j++) {
        float x = lw[(size_t)(kbase + j) * H_DIM + n];
        ushort h = f2bf(x);
        ushort l = f2bf(x - bf2f(h));
        hv[j] = h; lv[j] = l;
    }
    *reinterpret_cast<short8*>(lwfrag + ((size_t)(g * 2 + 0) * 64 + lane) * 8) =
        *reinterpret_cast<short8*>(hv);
    *reinterpret_cast<short8*>(lwfrag + ((size_t)(g * 2 + 1) * 64 + lane) * 8) =
        *reinterpret_cast<short8*>(lv);
}

__device__ __forceinline__ void prep_fc1_body(const float* __restrict__ w,
                                              ushort* __restrict__ wfrag, int t) {
    int lane = t & 63, g = t >> 6;
    int kt = g >> 5, ot = g & 31;
    int kbase = kt * 32 + (lane >> 4) * 8, n = ot * 16 + (lane & 15);
    ushort hv[8], lv[8];
#pragma unroll
    for (int j = 0; j < 8; j++) {
        float x = w[(size_t)(kbase + j) * D2 + n];
        ushort h = f2bf(x);
        ushort l = f2bf(x - bf2f(h));
        hv[j] = h; lv[j] = l;
    }
    *reinterpret_cast<short8*>(wfrag + ((size_t)(g * 2 + 0) * 64 + lane) * 8) =
        *reinterpret_cast<short8*>(hv);
    *reinterpret_cast<short8*>(wfrag + ((size_t)(g * 2 + 1) * 64 + lane) * 8) =
        *reinterpret_cast<short8*>(lv);
}

#define ZBLOCKS ((NBINS + 255) / 256)   // 1250

__global__ void k_prep_all(const float* __restrict__ w1, const float* __restrict__ w2,
                           const float* __restrict__ lw1, const float* __restrict__ lw2,
                           const float* __restrict__ fc1W,
                           ushort* __restrict__ wfrag1, ushort* __restrict__ wfrag2,
                           ushort* __restrict__ lwfrag1, ushort* __restrict__ lwfrag2,
                           ushort* __restrict__ fc1frag, int* __restrict__ segend) {
    int b = blockIdx.x, tid = threadIdx.x;
    if (b < 64)        prep_w_body(w1, wfrag1, b * 256 + tid);
    else if (b < 128)  prep_w_body(w2, wfrag2, (b - 64) * 256 + tid);
    else if (b < 160)  prep_lw_body(lw1, lwfrag1, (b - 128) * 256 + tid);
    else if (b < 192)  prep_lw_body(lw2, lwfrag2, (b - 160) * 256 + tid);
    else if (b < 320)  prep_fc1_body(fc1W, fc1frag, (b - 192) * 256 + tid);
    else {
        int i = (b - 320) * 256 + tid;
        if (i < NBINS) segend[i] = 0;
    }
}

// ---------------- fused RGCN-BDD layer (MFMA, bf16 hi/lo 3-term) ----------------
// block = 16 dst nodes, 512 threads = 8 waves. Per PHASE p (8 phases): the two
// relations ra=2p, rb=2p+1 are aggregated together — each wave runs 4 independent
// edge-chains (2 nodes x 2 rels) into two 16-row LDS buffers — then MFMAs both
// relations. LDS ~34 KB -> 4 blocks/CU (32 waves, ~128 resident chains/CU).
// Wave wv owns output cols 32wv..32wv+31 (b-block wv), acc[2] (ot=0,1).
__global__ __launch_bounds__(512) void k_layer(
    const float* __restrict__ hin, const uint* __restrict__ es, const int* __restrict__ segend,
    const ushort* __restrict__ wfrag, const ushort* __restrict__ lwfrag,
    const float* __restrict__ bias, float* __restrict__ hout) {
    __shared__ __align__(16) ushort aggH[2][TILE_N * H_DIM];
    __shared__ __align__(16) ushort aggLo[2][TILE_N * H_DIM];
    __shared__ int lofs[TILE_N * R_REL + 1];    // lofs[j]=beg of local bin j; [j+1]=end
    char* cH = (char*)aggH;
    char* cL = (char*)aggLo;
    const int n0 = blockIdx.x * TILE_N;
    const int tid = threadIdx.x;
    const int lane = tid & 63, wv = tid >> 6;
    const int col = lane & 15, kg = lane >> 4;
    const short8* wf  = (const short8*)wfrag;
    const short8* lwf = (const short8*)lwfrag;
    const uint laneoff = (uint)(lane << 2);
    const int t0 = 2 * wv;

    {   // block-local offset table (coalesced, once)
        const int base = n0 * R_REL;
        for (int j = tid; j < TILE_N * R_REL + 1; j += 512) {
            int g = base + j - 1;
            lofs[j] = (g < 0) ? 0 : segend[g];
        }
    }

    f32x4 acc[2];
    acc[0] = (f32x4){0.f, 0.f, 0.f, 0.f};
    acc[1] = (f32x4){0.f, 0.f, 0.f, 0.f};

    // pack a float4 to hi/lo bf16 and store to swizzled LDS (buffer base bb, row t)
    auto store_row = [&](float4 av, int t, uint bb) {
        ushort h0 = f2bf(av.x), h1 = f2bf(av.y), h2 = f2bf(av.z), h3 = f2bf(av.w);
        uint2 ph = make_uint2((uint)h0 | ((uint)h1 << 16), (uint)h2 | ((uint)h3 << 16));
        uint2 pl = make_uint2(
            (uint)f2bf(av.x - bf2f(h0)) | ((uint)f2bf(av.y - bf2f(h1)) << 16),
            (uint)f2bf(av.z - bf2f(h2)) | ((uint)f2bf(av.w - bf2f(h3)) << 16));
        uint byte = bb + (uint)(t * 512) +
                    ((((lane >> 1) ^ (t & 7)) << 4) | ((lane & 1) << 3));
        *(uint2*)(cH + byte) = ph;
        *(uint2*)(cL + byte) = pl;
    };

    for (int p = 0; p < 8; ++p) {
        const int ra = 2 * p, rb = ra + 1;
        __syncthreads();   // lofs ready (p=0) / previous MFMA reads done
        // ---- 4 independent chains: (node t0, ra), (t0, rb), (t0+1, ra), (t0+1, rb) ----
        int e00 = lofs[(t0 + 0) * R_REL + ra], d00 = lofs[(t0 + 0) * R_REL + ra + 1];
        int e01 = lofs[(t0 + 0) * R_REL + rb], d01 = lofs[(t0 + 0) * R_REL + rb + 1];
        int e10 = lofs[(t0 + 1) * R_REL + ra], d10 = lofs[(t0 + 1) * R_REL + ra + 1];
        int e11 = lofs[(t0 + 1) * R_REL + rb], d11 = lofs[(t0 + 1) * R_REL + rb + 1];
        float4 a00 = make_float4(0.f, 0.f, 0.f, 0.f);
        float4 a01 = make_float4(0.f, 0.f, 0.f, 0.f);
        float4 a10 = make_float4(0.f, 0.f, 0.f, 0.f);
        float4 a11 = make_float4(0.f, 0.f, 0.f, 0.f);
        while ((e00 < d00) | (e01 < d01) | (e10 < d10) | (e11 < d11)) {
            bool g00 = e00 < d00, g01 = e01 < d01, g10 = e10 < d10, g11 = e11 < d11;
            uint p00 = 0, p01 = 0, p10 = 0, p11 = 0;
            if (g00) p00 = es[e00++];
            if (g01) p01 = es[e01++];
            if (g10) p10 = es[e10++];
            if (g11) p11 = es[e11++];
            if (g00) {
                const float4 x = *reinterpret_cast<const float4*>(
                    hin + (size_t)(p00 >> 17) * H_DIM + laneoff);
                float nm = (float)(p00 & 0x1FFFFu) * (1.f / 131072.f);
                a00.x = fmaf(x.x, nm, a00.x); a00.y = fmaf(x.y, nm, a00.y);
                a00.z = fmaf(x.z, nm, a00.z); a00.w = fmaf(x.w, nm, a00.w);
            }
            if (g01) {
                const float4 x = *reinterpret_cast<const float4*>(
                    hin + (size_t)(p01 >> 17) * H_DIM + laneoff);
                float nm = (float)(p01 & 0x1FFFFu) * (1.f / 131072.f);
                a01.x = fmaf(x.x, nm, a01.x); a01.y = fmaf(x.y, nm, a01.y);
                a01.z = fmaf(x.z, nm, a01.z); a01.w = fmaf(x.w, nm, a01.w);
            }
            if (g10) {
                const float4 x = *reinterpret_cast<const float4*>(
                    hin + (size_t)(p10 >> 17) * H_DIM + laneoff);
                float nm = (float)(p10 & 0x1FFFFu) * (1.f / 131072.f);
                a10.x = fmaf(x.x, nm, a10.x); a10.y = fmaf(x.y, nm, a10.y);
                a10.z = fmaf(x.z, nm, a10.z); a10.w = fmaf(x.w, nm, a10.w);
            }
            if (g11) {
                const float4 x = *reinterpret_cast<const float4*>(
                    hin + (size_t)(p11 >> 17) * H_DIM + laneoff);
                float nm = (float)(p11 & 0x1FFFFu) * (1.f / 131072.f);
                a11.x = fmaf(x.x, nm, a11.x); a11.y = fmaf(x.y, nm, a11.y);
                a11.z = fmaf(x.z, nm, a11.z); a11.w = fmaf(x.w, nm, a11.w);
            }
        }
        store_row(a00, t0 + 0, 0);
        store_row(a01, t0 + 0, PLANE_B);
        store_row(a10, t0 + 1, 0);
        store_row(a11, t0 + 1, PLANE_B);
        __syncthreads();
        // ---- transform both relations: wave wv owns b-block wv ----
#pragma unroll
        for (int ri = 0; ri < 2; ++ri) {
            const int r = 2 * p + ri;
            const uint bb = (uint)ri * PLANE_B;
#pragma unroll
            for (int ot = 0; ot < 2; ++ot) {
                int f = (r * 8 + wv) * 2 + ot;
                short8 Bh = wf[(f * 2 + 0) * 64 + lane];
                short8 Bl = wf[(f * 2 + 1) * 64 + lane];
                int row = col;
                uint ab = bb + (uint)(row * 512) + ((uint)((wv * 4 + kg) ^ (row & 7)) << 4);
                short8 Ah = *(const short8*)(cH + ab);
                short8 Al = *(const short8*)(cL + ab);
                f32x4 a = acc[ot];
                a = __builtin_amdgcn_mfma_f32_16x16x32_bf16(Ah, Bh, a, 0, 0, 0);
                a = __builtin_amdgcn_mfma_f32_16x16x32_bf16(Ah, Bl, a, 0, 0, 0);
                a = __builtin_amdgcn_mfma_f32_16x16x32_bf16(Al, Bh, a, 0, 0, 0);
                acc[ot] = a;
            }
        }
    }

    // ---- self-loop: stage h tile into buf0, K=256 MFMA sweep ----
    __syncthreads();
#pragma unroll
    for (int i = 0; i < 2; ++i) {
        int t = t0 + i;
        const float4 xv = *reinterpret_cast<const float4*>(
            hin + (size_t)(n0 + t) * H_DIM + laneoff);
        store_row(xv, t, 0);
    }
    __syncthreads();
#pragma unroll
    for (int kt = 0; kt < 8; ++kt) {
#pragma unroll
        for (int ot = 0; ot < 2; ++ot) {
            int g = kt * 16 + 2 * wv + ot;
            short8 Bh = lwf[(g * 2 + 0) * 64 + lane];
            short8 Bl = lwf[(g * 2 + 1) * 64 + lane];
            int row = col;
            uint ab = (uint)(row * 512) + ((uint)((kt * 4 + kg) ^ (row & 7)) << 4);
            short8 Ah = *(const short8*)(cH + ab);
            short8 Al = *(const short8*)(cL + ab);
            f32x4 a = acc[ot];
            a = __builtin_amdgcn_mfma_f32_16x16x32_bf16(Ah, Bh, a, 0, 0, 0);
            a = __builtin_amdgcn_mfma_f32_16x16x32_bf16(Ah, Bl, a, 0, 0, 0);
            a = __builtin_amdgcn_mfma_f32_16x16x32_bf16(Al, Bh, a, 0, 0, 0);
            acc[ot] = a;
        }
    }

    // ---- epilogue: C/D layout col=lane&15, row=(lane>>4)*4+reg ----
    {
        int nbase = n0 + kg * 4;
#pragma unroll
        for (int ot = 0; ot < 2; ++ot) {
            int o = 32 * wv + ot * 16 + col;
            float bo = bias[o];
#pragma unroll
            for (int rg = 0; rg < 4; ++rg)
                hout[(size_t)(nbase + rg) * H_DIM + o] = acc[ot][rg] + bo;
        }
    }
}

// ---------------- fused concat + fc1(MFMA) + relu + fc2 + sigmoid ----------------
__global__ __launch_bounds__(512) void k_mlp(
    const float* __restrict__ h, const int* __restrict__ drugs, const int* __restrict__ targets,
    const ushort* __restrict__ fc1frag, const float* __restrict__ b1f,
    const float* __restrict__ W2, const float* __restrict__ b2f,
    float* __restrict__ outp) {
    __shared__ __align__(16) ushort xH[16 * D2];
    __shared__ __align__(16) ushort xL[16 * D2];
    __shared__ float red[16][8];
    char* cH = (char*)xH;
    char* cL = (char*)xL;
    const int tid = threadIdx.x;
    const int lane = tid & 63, wv = tid >> 6;
    const int col = lane & 15, kg = lane >> 4;
    const int p0 = blockIdx.x * 16;
    const short8* wf = (const short8*)fc1frag;

    {   // stage X = [h[drug] | h[target]] as bf16 hi/lo, swizzled
        int p = tid >> 5;
        int cc = (tid & 31) * 16;
        int di = drugs[p0 + p], ti = targets[p0 + p];
        const float* srcp = (cc < H_DIM) ? (h + (size_t)di * H_DIM + cc)
                                         : (h + (size_t)ti * H_DIM + (cc - H_DIM));
#pragma unroll
        for (int j = 0; j < 2; ++j) {
            float4 a = *reinterpret_cast<const float4*>(srcp + j * 8);
            float4 b = *reinterpret_cast<const float4*>(srcp + j * 8 + 4);
            float f[8] = {a.x, a.y, a.z, a.w, b.x, b.y, b.z, b.w};
            short8 hv, lv;
#pragma unroll
            for (int q = 0; q < 8; ++q) {
                ushort hh = f2bf(f[q]);
                hv[q] = (short)hh;
                lv[q] = (short)f2bf(f[q] - bf2f(hh));
            }
            uint chunk = (uint)((tid & 31) * 2 + j);
            uint byte = (uint)p * 1024 + ((chunk ^ (uint)(p & 7)) << 4);
            *(short8*)(cH + byte) = hv;
            *(short8*)(cL + byte) = lv;
        }
    }
    __syncthreads();

    f32x4 acc[4];
#pragma unroll
    for (int oi = 0; oi < 4; ++oi) acc[oi] = (f32x4){0.f, 0.f, 0.f, 0.f};

    for (int kt = 0; kt < 16; ++kt) {
        uint ab = (uint)col * 1024 + ((uint)((kt * 4 + kg) ^ (col & 7)) << 4);
        short8 Ah = *(const short8*)(cH + ab);
        short8 Al = *(const short8*)(cL + ab);
#pragma unroll
        for (int oi = 0; oi < 4; ++oi) {
            int g = kt * 32 + wv * 4 + oi;
            short8 Bh = wf[(g * 2 + 0) * 64 + lane];
            short8 Bl = wf[(g * 2 + 1) * 64 + lane];
            f32x4 a = acc[oi];
            a = __builtin_amdgcn_mfma_f32_16x16x32_bf16(Ah, Bh, a, 0, 0, 0);
            a = __builtin_amdgcn_mfma_f32_16x16x32_bf16(Ah, Bl, a, 0, 0, 0);
            a = __builtin_amdgcn_mfma_f32_16x16x32_bf16(Al, Bh, a, 0, 0, 0);
            a = __builtin_amdgcn_mfma_f32_16x16x32_bf16(Al, Bl, a, 0, 0, 0);
            acc[oi] = a;
        }
    }

    float val[4] = {0.f, 0.f, 0.f, 0.f};
#pragma unroll
    for (int oi = 0; oi < 4; ++oi) {
        int o = 64 * wv + oi * 16 + col;
        float b1o = b1f[o], w2o = W2[o];
#pragma unroll
        for (int rg = 0; rg < 4; ++rg) {
            float y = acc[oi][rg] + b1o;
            y = y > 0.f ? y : 0.f;
            val[rg] = fmaf(y, w2o, val[rg]);
        }
    }
#pragma unroll
    for (int rg = 0; rg < 4; ++rg) {
        float v = val[rg];
        v += __shfl_xor(v, 1, 64);
        v += __shfl_xor(v, 2, 64);
        v += __shfl_xor(v, 4, 64);
        v += __shfl_xor(v, 8, 64);
        val[rg] = v;
    }
    if (col == 0) {
#pragma unroll
        for (int rg = 0; rg < 4; ++rg) red[kg * 4 + rg][wv] = val[rg];
    }
    __syncthreads();
    if (tid < 16) {
        float s = 0.f;
#pragma unroll
        for (int w = 0; w < 8; w++) s += red[tid][w];
        s += b2f[0];
        outp[p0 + tid] = 1.f / (1.f + __expf(-s));
    }
}

extern "C" void kernel_launch(void* const* d_in, const int* in_sizes, int n_in,
                              void* d_out, int out_size, void* d_ws, size_t ws_size,
                              hipStream_t stream) {
    (void)in_sizes; (void)n_in; (void)out_size; (void)ws_size;
    const int*   drugs   = (const int*)d_in[0];
    const int*   targets = (const int*)d_in[1];
    const int*   nid     = (const int*)d_in[2];
    const int*   src     = (const int*)d_in[3];
    const int*   dst     = (const int*)d_in[4];
    const int*   ety     = (const int*)d_in[5];
    const float* nrm     = (const float*)d_in[6];
    const float* emb     = (const float*)d_in[7];
    const float* w1      = (const float*)d_in[8];
    const float* lw1     = (const float*)d_in[9];
    const float* b1      = (const float*)d_in[10];
    const float* w2      = (const float*)d_in[11];
    const float* lw2     = (const float*)d_in[12];
    const float* b2      = (const float*)d_in[13];
    const float* fc1W    = (const float*)d_in[14];
    const float* fc1b    = (const float*)d_in[15];
    const float* fc2W    = (const float*)d_in[16];
    const float* fc2b    = (const float*)d_in[17];
    float* outp = (float*)d_out;

    // ws layout — total 46,462,464 B (within proven budget).
    char* ws = (char*)d_ws;
    ushort* wfrag1  = (ushort*)(ws);                    //    524,288
    ushort* wfrag2  = (ushort*)(ws + 524288);           //    524,288
    ushort* lwfrag1 = (ushort*)(ws + 1048576);          //    262,144
    ushort* lwfrag2 = (ushort*)(ws + 1310720);          //    262,144
    ushort* fc1frag = (ushort*)(ws + 1572864);          //  1,048,576
    float*  hA      = (float*) (ws + 2621440);          // 20,480,000
    float*  hB      = (float*) (ws + 23101440);         // 20,480,000
    int*    segend  = (int*)   (ws + 43581440);         //  1,280,000
    int*    bs      = (int*)   (ws + 44861440);         //      1,024
    uint*   es      = (uint*)  (ws + 44862464);         //  1,600,000 -> end 46,462,464

    k_prep_all<<<320 + ZBLOCKS, 256, 0, stream>>>(w1, w2, lw1, lw2, fc1W,
                                                  wfrag1, wfrag2, lwfrag1, lwfrag2,
                                                  fc1frag, segend);
    k_gather <<<5000, 256, 0, stream>>>(emb, nid, hA);
    k_count  <<<(E_EDGES + 255) / 256, 256, 0, stream>>>(dst, ety, segend);
    k_scan1  <<<NSCAN_BLOCKS, 256, 0, stream>>>(segend, bs);
    k_scan2  <<<1, 256, 0, stream>>>(bs);
    k_scan3  <<<(NBINS + 255) / 256, 256, 0, stream>>>(segend, bs);
    k_scatter<<<(E_EDGES + 255) / 256, 256, 0, stream>>>(src, dst, ety, nrm, segend, es);
    k_layer  <<<NT_BLOCKS, 512, 0, stream>>>(hA, es, segend, wfrag1, lwfrag1, b1, hB);
    k_layer  <<<NT_BLOCKS, 512, 0, stream>>>(hB, es, segend, wfrag2, lwfrag2, b2, hA);
    k_mlp    <<<NPAIRS / 16, 512, 0, stream>>>(hA, drugs, targets, fc1frag, fc1b, fc2W, fc2b, outp);
}

// Round 10
// 276.691 us; speedup vs baseline: 1.4813x; 1.1168x over previous
//
#include <hip/hip_runtime.h>
#include <math.h>

typedef __attribute__((ext_vector_type(8))) short short8;
typedef __attribute__((ext_vector_type(4))) float f32x4;

#define N_SUBN   20000
#define E_EDGES  400000
#define R_REL    16
#define H_DIM    256
#define NBINS    (N_SUBN * R_REL)          // 320000 (dst,rel) buckets
#define SCAN_CHUNK 2048
#define NSCAN_BLOCKS ((NBINS + SCAN_CHUNK - 1) / SCAN_CHUNK)   // 157
#define NPAIRS   4096
#define TILE_N   32
#define NT_BLOCKS (N_SUBN / TILE_N)                            // 625 exact
#define D2       512
#define ECAP     1024                      // LDS edge-cache capacity (avg ~640/block)

// ---- bf16 hi/lo split helpers (RNE) ----
__device__ __forceinline__ ushort f2bf(float x) {
    uint u = __float_as_uint(x);
    u += 0x7fffu + ((u >> 16) & 1u);
    return (ushort)(u >> 16);
}
__device__ __forceinline__ float bf2f(ushort h) {
    return __uint_as_float(((uint)h) << 16);
}

// ---------------- gather: h0 = emb[node_ids] ----------------
__global__ void k_gather(const float* __restrict__ emb, const int* __restrict__ nid,
                         float* __restrict__ h0) {
    int t = blockIdx.x * blockDim.x + threadIdx.x;   // 20000*64 float4 slots
    int node = t >> 6, c = (t & 63) << 2;
    if (node >= N_SUBN) return;
    const float4 s = *reinterpret_cast<const float4*>(emb + (size_t)nid[node] * H_DIM + c);
    *reinterpret_cast<float4*>(h0 + (size_t)node * H_DIM + c) = s;
}

// ---------------- CSR build over bin = dst*R + etype ----------------
__global__ void k_count(const int* __restrict__ dst, const int* __restrict__ ety,
                        int* __restrict__ cnt) {
    int e = blockIdx.x * 256 + threadIdx.x;
    if (e < E_EDGES) atomicAdd(&cnt[dst[e] * R_REL + ety[e]], 1);
}

__global__ void k_scan1(int* __restrict__ data, int* __restrict__ bs) {
    __shared__ int ts[256];
    int base = blockIdx.x * SCAN_CHUNK + threadIdx.x * 8;
    int v[8]; int s = 0;
#pragma unroll
    for (int j = 0; j < 8; j++) {
        int idx = base + j;
        v[j] = (idx < NBINS) ? data[idx] : 0;
        s += v[j];
    }
    ts[threadIdx.x] = s;
    __syncthreads();
    for (int off = 1; off < 256; off <<= 1) {
        int add = (threadIdx.x >= (unsigned)off) ? ts[threadIdx.x - off] : 0;
        __syncthreads();
        ts[threadIdx.x] += add;
        __syncthreads();
    }
    int excl = ts[threadIdx.x] - s;
    if (threadIdx.x == 255) bs[blockIdx.x] = ts[255];
    int run = excl;
#pragma unroll
    for (int j = 0; j < 8; j++) {
        int idx = base + j;
        if (idx < NBINS) data[idx] = run;
        run += v[j];
    }
}

__global__ void k_scan2(int* __restrict__ bs) {
    __shared__ int ls[NSCAN_BLOCKS];
    if (threadIdx.x < NSCAN_BLOCKS) ls[threadIdx.x] = bs[threadIdx.x];
    __syncthreads();
    if (threadIdx.x == 0) {
        int run = 0;
        for (int i = 0; i < NSCAN_BLOCKS; i++) { int t = ls[i]; ls[i] = run; run += t; }
    }
    __syncthreads();
    if (threadIdx.x < NSCAN_BLOCKS) bs[threadIdx.x] = ls[threadIdx.x];
}

__global__ void k_scan3(int* __restrict__ data, const int* __restrict__ bs) {
    int idx = blockIdx.x * 256 + threadIdx.x;
    if (idx < NBINS) data[idx] = data[idx] + bs[idx / SCAN_CHUNK];
}

// scatter increments segend in place: post-scatter segend[bin] = END of bin,
// beg(bin) = (bin==0) ? 0 : segend[bin-1]. Edge packed: (src<<17) | norm_q17.
__global__ void k_scatter(const int* __restrict__ src, const int* __restrict__ dst,
                          const int* __restrict__ ety, const float* __restrict__ nrm,
                          int* __restrict__ segend, uint* __restrict__ es) {
    int e = blockIdx.x * 256 + threadIdx.x;
    if (e >= E_EDGES) return;
    int bin = dst[e] * R_REL + ety[e];
    int pos = atomicAdd(&segend[bin], 1);
    float n = nrm[e];
    uint q = (uint)fminf(n * 131072.f + 0.5f, 131071.f);
    es[pos] = ((uint)src[e] << 17) | q;
}

// ---------------- combined pre-pack + segend zero (one dispatch) ----------------
__device__ __forceinline__ void prep_w_body(const float* __restrict__ w,
                                            ushort* __restrict__ wfrag, int t) {
    int lane = t & 63, f = t >> 6;
    int ot = f & 1, rb = f >> 1;              // rb = r*8+b
    int kbase = (lane >> 4) * 8, n = ot * 16 + (lane & 15);
    ushort hv[8], lv[8];
#pragma unroll
    for (int j = 0; j < 8; j++) {
        float x = w[(size_t)(rb * 32 + kbase + j) * 32 + n];
        ushort h = f2bf(x);
        ushort l = f2bf(x - bf2f(h));
        hv[j] = h; lv[j] = l;
    }
    *reinterpret_cast<short8*>(wfrag + ((size_t)(f * 2 + 0) * 64 + lane) * 8) =
        *reinterpret_cast<short8*>(hv);
    *reinterpret_cast<short8*>(wfrag + ((size_t)(f * 2 + 1) * 64 + lane) * 8) =
        *reinterpret_cast<short8*>(lv);
}

__device__ __forceinline__ void prep_lw_body(const float* __restrict__ lw,
                                             ushort* __restrict__ lwfrag, int t) {
    int lane = t & 63, g = t >> 6;
    int kt = g >> 4, ot = g & 15;
    int kbase = kt * 32 + (lane >> 4) * 8, n = ot * 16 + (lane & 15);
    ushort hv[8], lv[8];
#pragma unroll
    for (int j = 0; j < 8; j++) {
        float x = lw[(size_t)(kbase + j) * H_DIM + n];
        ushort h = f2bf(x);
        ushort l = f2bf(x - bf2f(h));
        hv[j] = h; lv[j] = l;
    }
    *reinterpret_cast<short8*>(lwfrag + ((size_t)(g * 2 + 0) * 64 + lane) * 8) =
        *reinterpret_cast<short8*>(hv);
    *reinterpret_cast<short8*>(lwfrag + ((size_t)(g * 2 + 1) * 64 + lane) * 8) =
        *reinterpret_cast<short8*>(lv);
}

__device__ __forceinline__ void prep_fc1_body(const float* __restrict__ w,
                                              ushort* __restrict__ wfrag, int t) {
    int lane = t & 63, g = t >> 6;
    int kt = g >> 5, ot = g & 31;
    int kbase = kt * 32 + (lane >> 4) * 8, n = ot * 16 + (lane & 15);
    ushort hv[8], lv[8];
#pragma unroll
    for (int j = 0; j < 8; j++) {
        float x = w[(size_t)(kbase + j) * D2 + n];
        ushort h = f2bf(x);
        ushort l = f2bf(x - bf2f(h));
        hv[j] = h; lv[j] = l;
    }
    *reinterpret_cast<short8*>(wfrag + ((size_t)(g * 2 + 0) * 64 + lane) * 8) =
        *reinterpret_cast<short8*>(hv);
    *reinterpret_cast<short8*>(wfrag + ((size_t)(g * 2 + 1) * 64 + lane) * 8) =
        *reinterpret_cast<short8*>(lv);
}

#define ZBLOCKS ((NBINS + 255) / 256)   // 1250

__global__ void k_prep_all(const float* __restrict__ w1, const float* __restrict__ w2,
                           const float* __restrict__ lw1, const float* __restrict__ lw2,
                           const float* __restrict__ fc1W,
                           ushort* __restrict__ wfrag1, ushort* __restrict__ wfrag2,
                           ushort* __restrict__ lwfrag1, ushort* __restrict__ lwfrag2,
                           ushort* __restrict__ fc1frag, int* __restrict__ segend) {
    int b = blockIdx.x, tid = threadIdx.x;
    if (b < 64)        prep_w_body(w1, wfrag1, b * 256 + tid);
    else if (b < 128)  prep_w_body(w2, wfrag2, (b - 64) * 256 + tid);
    else if (b < 160)  prep_lw_body(lw1, lwfrag1, (b - 128) * 256 + tid);
    else if (b < 192)  prep_lw_body(lw2, lwfrag2, (b - 160) * 256 + tid);
    else if (b < 320)  prep_fc1_body(fc1W, fc1frag, (b - 192) * 256 + tid);
    else {
        int i = (b - 320) * 256 + tid;
        if (i < NBINS) segend[i] = 0;
    }
}

// ---------------- fused RGCN-BDD layer (MFMA, bf16 hi/lo 3-term) ----------------
// Round-6 proven structure (TILE 32, 512 thr = 8 waves, wave owns 4 nodes via
// 4 interleaved edge cursors, single LDS buffer, 2 barriers/rel) PLUS a
// block-level LDS edge cache: the block's edges are contiguous in es
// ([lofs[0], lofs[512]), avg ~640); prefetch up to ECAP once (coalesced),
// then all per-edge reads are wave-uniform ds_reads (no random global loads
// on the dependent chain). Global fallback beyond ECAP keeps correctness.
__global__ __launch_bounds__(512) void k_layer(
    const float* __restrict__ hin, const uint* __restrict__ es, const int* __restrict__ segend,
    const ushort* __restrict__ wfrag, const ushort* __restrict__ lwfrag,
    const float* __restrict__ bias, float* __restrict__ hout) {
    __shared__ __align__(16) ushort aggH[TILE_N * H_DIM];
    __shared__ __align__(16) ushort aggLo[TILE_N * H_DIM];
    __shared__ int lofs[TILE_N * R_REL + 1];    // lofs[j]=beg of local bin j; [j+1]=end
    __shared__ uint les[ECAP];                  // block-local edge cache
    char* cH = (char*)aggH;
    char* cL = (char*)aggLo;
    const int n0 = blockIdx.x * TILE_N;
    const int tid = threadIdx.x;
    const int lane = tid & 63, wv = tid >> 6;
    const int col = lane & 15, kg = lane >> 4;
    const short8* wf  = (const short8*)wfrag;
    const short8* lwf = (const short8*)lwfrag;
    const uint laneoff = (uint)(lane << 2);
    const int t0 = 4 * wv;

    {   // block-local offset table (coalesced, once)
        const int base = n0 * R_REL;
        for (int j = tid; j < TILE_N * R_REL + 1; j += 512) {
            int g = base + j - 1;
            lofs[j] = (g < 0) ? 0 : segend[g];
        }
    }
    __syncthreads();
    const int ebase = lofs[0];
    const int elim  = min(lofs[TILE_N * R_REL] - ebase, ECAP);
    for (int j = tid; j < elim; j += 512) les[j] = es[ebase + j];
    // first loop-top __syncthreads() publishes les

    f32x4 acc[2][2];
#pragma unroll
    for (int mt = 0; mt < 2; ++mt)
#pragma unroll
        for (int ot = 0; ot < 2; ++ot) acc[mt][ot] = (f32x4){0.f, 0.f, 0.f, 0.f};

    for (int r = 0; r < R_REL; ++r) {
        __syncthreads();   // les/lofs ready (r=0) / previous MFMA reads done
        // ---- 4-way interleaved aggregation of nodes t0..t0+3 ----
        int e0 = lofs[(t0 + 0) * R_REL + r], d0 = lofs[(t0 + 0) * R_REL + r + 1];
        int e1 = lofs[(t0 + 1) * R_REL + r], d1 = lofs[(t0 + 1) * R_REL + r + 1];
        int e2 = lofs[(t0 + 2) * R_REL + r], d2 = lofs[(t0 + 2) * R_REL + r + 1];
        int e3 = lofs[(t0 + 3) * R_REL + r], d3 = lofs[(t0 + 3) * R_REL + r + 1];
        float4 a0 = make_float4(0.f, 0.f, 0.f, 0.f);
        float4 a1 = make_float4(0.f, 0.f, 0.f, 0.f);
        float4 a2 = make_float4(0.f, 0.f, 0.f, 0.f);
        float4 a3 = make_float4(0.f, 0.f, 0.f, 0.f);
        while ((e0 < d0) | (e1 < d1) | (e2 < d2) | (e3 < d3)) {
            bool g0 = e0 < d0, g1 = e1 < d1, g2 = e2 < d2, g3 = e3 < d3;
            uint p0 = 0, p1 = 0, p2 = 0, p3 = 0;
            if (g0) { int i = e0 - ebase; p0 = (i < ECAP) ? les[i] : es[e0]; ++e0; }
            if (g1) { int i = e1 - ebase; p1 = (i < ECAP) ? les[i] : es[e1]; ++e1; }
            if (g2) { int i = e2 - ebase; p2 = (i < ECAP) ? les[i] : es[e2]; ++e2; }
            if (g3) { int i = e3 - ebase; p3 = (i < ECAP) ? les[i] : es[e3]; ++e3; }
            if (g0) {
                const float4 x = *reinterpret_cast<const float4*>(
                    hin + (size_t)(p0 >> 17) * H_DIM + laneoff);
                float nm = (float)(p0 & 0x1FFFFu) * (1.f / 131072.f);
                a0.x = fmaf(x.x, nm, a0.x); a0.y = fmaf(x.y, nm, a0.y);
                a0.z = fmaf(x.z, nm, a0.z); a0.w = fmaf(x.w, nm, a0.w);
            }
            if (g1) {
                const float4 x = *reinterpret_cast<const float4*>(
                    hin + (size_t)(p1 >> 17) * H_DIM + laneoff);
                float nm = (float)(p1 & 0x1FFFFu) * (1.f / 131072.f);
                a1.x = fmaf(x.x, nm, a1.x); a1.y = fmaf(x.y, nm, a1.y);
                a1.z = fmaf(x.z, nm, a1.z); a1.w = fmaf(x.w, nm, a1.w);
            }
            if (g2) {
                const float4 x = *reinterpret_cast<const float4*>(
                    hin + (size_t)(p2 >> 17) * H_DIM + laneoff);
                float nm = (float)(p2 & 0x1FFFFu) * (1.f / 131072.f);
                a2.x = fmaf(x.x, nm, a2.x); a2.y = fmaf(x.y, nm, a2.y);
                a2.z = fmaf(x.z, nm, a2.z); a2.w = fmaf(x.w, nm, a2.w);
            }
            if (g3) {
                const float4 x = *reinterpret_cast<const float4*>(
                    hin + (size_t)(p3 >> 17) * H_DIM + laneoff);
                float nm = (float)(p3 & 0x1FFFFu) * (1.f / 131072.f);
                a3.x = fmaf(x.x, nm, a3.x); a3.y = fmaf(x.y, nm, a3.y);
                a3.z = fmaf(x.z, nm, a3.z); a3.w = fmaf(x.w, nm, a3.w);
            }
        }
#pragma unroll
        for (int i = 0; i < 4; ++i) {
            float4 av = (i == 0) ? a0 : (i == 1) ? a1 : (i == 2) ? a2 : a3;
            int t = t0 + i;
            ushort h0 = f2bf(av.x), h1 = f2bf(av.y), h2 = f2bf(av.z), h3 = f2bf(av.w);
            uint2 ph = make_uint2((uint)h0 | ((uint)h1 << 16), (uint)h2 | ((uint)h3 << 16));
            uint2 pl = make_uint2(
                (uint)f2bf(av.x - bf2f(h0)) | ((uint)f2bf(av.y - bf2f(h1)) << 16),
                (uint)f2bf(av.z - bf2f(h2)) | ((uint)f2bf(av.w - bf2f(h3)) << 16));
            uint byte = (uint)(t * 512) + ((((lane >> 1) ^ (t & 7)) << 4) | ((lane & 1) << 3));
            *(uint2*)(cH + byte) = ph;
            *(uint2*)(cL + byte) = pl;
        }
        __syncthreads();
        // ---- transform: wave wv owns b-block wv ----
#pragma unroll
        for (int ot = 0; ot < 2; ++ot) {
            int f = (r * 8 + wv) * 2 + ot;
            short8 Bh = wf[(f * 2 + 0) * 64 + lane];
            short8 Bl = wf[(f * 2 + 1) * 64 + lane];
#pragma unroll
            for (int mt = 0; mt < 2; ++mt) {
                int row = mt * 16 + col;
                uint ab = (uint)(row * 512) + ((uint)((wv * 4 + kg) ^ (row & 7)) << 4);
                short8 Ah = *(const short8*)(cH + ab);
                short8 Al = *(const short8*)(cL + ab);
                f32x4 a = acc[mt][ot];
                a = __builtin_amdgcn_mfma_f32_16x16x32_bf16(Ah, Bh, a, 0, 0, 0);
                a = __builtin_amdgcn_mfma_f32_16x16x32_bf16(Ah, Bl, a, 0, 0, 0);
                a = __builtin_amdgcn_mfma_f32_16x16x32_bf16(Al, Bh, a, 0, 0, 0);
                acc[mt][ot] = a;
            }
        }
    }

    // ---- self-loop: restage h tile as hi/lo, K=256 MFMA sweep ----
    __syncthreads();
#pragma unroll
    for (int i = 0; i < 4; ++i) {
        int t = t0 + i;
        const float4 xv = *reinterpret_cast<const float4*>(
            hin + (size_t)(n0 + t) * H_DIM + laneoff);
        ushort h0 = f2bf(xv.x), h1 = f2bf(xv.y), h2 = f2bf(xv.z), h3 = f2bf(xv.w);
        uint2 ph = make_uint2((uint)h0 | ((uint)h1 << 16), (uint)h2 | ((uint)h3 << 16));
        uint2 pl = make_uint2(
            (uint)f2bf(xv.x - bf2f(h0)) | ((uint)f2bf(xv.y - bf2f(h1)) << 16),
            (uint)f2bf(xv.z - bf2f(h2)) | ((uint)f2bf(xv.w - bf2f(h3)) << 16));
        uint byte = (uint)(t * 512) + ((((lane >> 1) ^ (t & 7)) << 4) | ((lane & 1) << 3));
        *(uint2*)(cH + byte) = ph;
        *(uint2*)(cL + byte) = pl;
    }
    __syncthreads();
#pragma unroll
    for (int kt = 0; kt < 8; ++kt) {
#pragma unroll
        for (int ot = 0; ot < 2; ++ot) {
            int g = kt * 16 + 2 * wv + ot;
            short8 Bh = lwf[(g * 2 + 0) * 64 + lane];
            short8 Bl = lwf[(g * 2 + 1) * 64 + lane];
#pragma unroll
            for (int mt = 0; mt < 2; ++mt) {
                int row = mt * 16 + col;
                uint ab = (uint)(row * 512) + ((uint)((kt * 4 + kg) ^ (row & 7)) << 4);
                short8 Ah = *(const short8*)(cH + ab);
                short8 Al = *(const short8*)(cL + ab);
                f32x4 a = acc[mt][ot];
                a = __builtin_amdgcn_mfma_f32_16x16x32_bf16(Ah, Bh, a, 0, 0, 0);
                a = __builtin_amdgcn_mfma_f32_16x16x32_bf16(Ah, Bl, a, 0, 0, 0);
                a = __builtin_amdgcn_mfma_f32_16x16x32_bf16(Al, Bh, a, 0, 0, 0);
                acc[mt][ot] = a;
            }
        }
    }

    // ---- epilogue: C/D layout col=lane&15, row=(lane>>4)*4+reg ----
#pragma unroll
    for (int mt = 0; mt < 2; ++mt) {
        int nbase = n0 + mt * 16 + kg * 4;
#pragma unroll
        for (int ot = 0; ot < 2; ++ot) {
            int o = 32 * wv + ot * 16 + col;
            float bo = bias[o];
#pragma unroll
            for (int rg = 0; rg < 4; ++rg)
                hout[(size_t)(nbase + rg) * H_DIM + o] = acc[mt][ot][rg] + bo;
        }
    }
}

// ---------------- fused concat + fc1(MFMA) + relu + fc2 + sigmoid ----------------
__global__ __launch_bounds__(512) void k_mlp(
    const float* __restrict__ h, const int* __restrict__ drugs, const int* __restrict__ targets,
    const ushort* __restrict__ fc1frag, const float* __restrict__ b1f,
    const float* __restrict__ W2, const float* __restrict__ b2f,
    float* __restrict__ outp) {
    __shared__ __align__(16) ushort xH[16 * D2];
    __shared__ __align__(16) ushort xL[16 * D2];
    __shared__ float red[16][8];
    char* cH = (char*)xH;
    char* cL = (char*)xL;
    const int tid = threadIdx.x;
    const int lane = tid & 63, wv = tid >> 6;
    const int col = lane & 15, kg = lane >> 4;
    const int p0 = blockIdx.x * 16;
    const short8* wf = (const short8*)fc1frag;

    {   // stage X = [h[drug] | h[target]] as bf16 hi/lo, swizzled
        int p = tid >> 5;
        int cc = (tid & 31) * 16;
        int di = drugs[p0 + p], ti = targets[p0 + p];
        const float* srcp = (cc < H_DIM) ? (h + (size_t)di * H_DIM + cc)
                                         : (h + (size_t)ti * H_DIM + (cc - H_DIM));
#pragma unroll
        for (int j = 0; j < 2; ++j) {
            float4 a = *reinterpret_cast<const float4*>(srcp + j * 8);
            float4 b = *reinterpret_cast<const float4*>(srcp + j * 8 + 4);
            float f[8] = {a.x, a.y, a.z, a.w, b.x, b.y, b.z, b.w};
            short8 hv, lv;
#pragma unroll
            for (int q = 0; q < 8; ++q) {
                ushort hh = f2bf(f[q]);
                hv[q] = (short)hh;
                lv[q] = (short)f2bf(f[q] - bf2f(hh));
            }
            uint chunk = (uint)((tid & 31) * 2 + j);
            uint byte = (uint)p * 1024 + ((chunk ^ (uint)(p & 7)) << 4);
            *(short8*)(cH + byte) = hv;
            *(short8*)(cL + byte) = lv;
        }
    }
    __syncthreads();

    f32x4 acc[4];
#pragma unroll
    for (int oi = 0; oi < 4; ++oi) acc[oi] = (f32x4){0.f, 0.f, 0.f, 0.f};

    for (int kt = 0; kt < 16; ++kt) {
        uint ab = (uint)col * 1024 + ((uint)((kt * 4 + kg) ^ (col & 7)) << 4);
        short8 Ah = *(const short8*)(cH + ab);
        short8 Al = *(const short8*)(cL + ab);
#pragma unroll
        for (int oi = 0; oi < 4; ++oi) {
            int g = kt * 32 + wv * 4 + oi;
            short8 Bh = wf[(g * 2 + 0) * 64 + lane];
            short8 Bl = wf[(g * 2 + 1) * 64 + lane];
            f32x4 a = acc[oi];
            a = __builtin_amdgcn_mfma_f32_16x16x32_bf16(Ah, Bh, a, 0, 0, 0);
            a = __builtin_amdgcn_mfma_f32_16x16x32_bf16(Ah, Bl, a, 0, 0, 0);
            a = __builtin_amdgcn_mfma_f32_16x16x32_bf16(Al, Bh, a, 0, 0, 0);
            a = __builtin_amdgcn_mfma_f32_16x16x32_bf16(Al, Bl, a, 0, 0, 0);
            acc[oi] = a;
        }
    }

    float val[4] = {0.f, 0.f, 0.f, 0.f};
#pragma unroll
    for (int oi = 0; oi < 4; ++oi) {
        int o = 64 * wv + oi * 16 + col;
        float b1o = b1f[o], w2o = W2[o];
#pragma unroll
        for (int rg = 0; rg < 4; ++rg) {
            float y = acc[oi][rg] + b1o;
            y = y > 0.f ? y : 0.f;
            val[rg] = fmaf(y, w2o, val[rg]);
        }
    }
#pragma unroll
    for (int rg = 0; rg < 4; ++rg) {
        float v = val[rg];
        v += __shfl_xor(v, 1, 64);
        v += __shfl_xor(v, 2, 64);
        v += __shfl_xor(v, 4, 64);
        v += __shfl_xor(v, 8, 64);
        val[rg] = v;
    }
    if (col == 0) {
#pragma unroll
        for (int rg = 0; rg < 4; ++rg) red[kg * 4 + rg][wv] = val[rg];
    }
    __syncthreads();
    if (tid < 16) {
        float s = 0.f;
#pragma unroll
        for (int w = 0; w < 8; w++) s += red[tid][w];
        s += b2f[0];
        outp[p0 + tid] = 1.f / (1.f + __expf(-s));
    }
}

extern "C" void kernel_launch(void* const* d_in, const int* in_sizes, int n_in,
                              void* d_out, int out_size, void* d_ws, size_t ws_size,
                              hipStream_t stream) {
    (void)in_sizes; (void)n_in; (void)out_size; (void)ws_size;
    const int*   drugs   = (const int*)d_in[0];
    const int*   targets = (const int*)d_in[1];
    const int*   nid     = (const int*)d_in[2];
    const int*   src     = (const int*)d_in[3];
    const int*   dst     = (const int*)d_in[4];
    const int*   ety     = (const int*)d_in[5];
    const float* nrm     = (const float*)d_in[6];
    const float* emb     = (const float*)d_in[7];
    const float* w1      = (const float*)d_in[8];
    const float* lw1     = (const float*)d_in[9];
    const float* b1      = (const float*)d_in[10];
    const float* w2      = (const float*)d_in[11];
    const float* lw2     = (const float*)d_in[12];
    const float* b2      = (const float*)d_in[13];
    const float* fc1W    = (const float*)d_in[14];
    const float* fc1b    = (const float*)d_in[15];
    const float* fc2W    = (const float*)d_in[16];
    const float* fc2b    = (const float*)d_in[17];
    float* outp = (float*)d_out;

    // ws layout — total 46,462,464 B (within proven budget).
    char* ws = (char*)d_ws;
    ushort* wfrag1  = (ushort*)(ws);                    //    524,288
    ushort* wfrag2  = (ushort*)(ws + 524288);           //    524,288
    ushort* lwfrag1 = (ushort*)(ws + 1048576);          //    262,144
    ushort* lwfrag2 = (ushort*)(ws + 1310720);          //    262,144
    ushort* fc1frag = (ushort*)(ws + 1572864);          //  1,048,576
    float*  hA      = (float*) (ws + 2621440);          // 20,480,000
    float*  hB      = (float*) (ws + 23101440);         // 20,480,000
    int*    segend  = (int*)   (ws + 43581440);         //  1,280,000
    int*    bs      = (int*)   (ws + 44861440);         //      1,024
    uint*   es      = (uint*)  (ws + 44862464);         //  1,600,000 -> end 46,462,464

    k_prep_all<<<320 + ZBLOCKS, 256, 0, stream>>>(w1, w2, lw1, lw2, fc1W,
                                                  wfrag1, wfrag2, lwfrag1, lwfrag2,
                                                  fc1frag, segend);
    k_gather <<<5000, 256, 0, stream>>>(emb, nid, hA);
    k_count  <<<(E_EDGES + 255) / 256, 256, 0, stream>>>(dst, ety, segend);
    k_scan1  <<<NSCAN_BLOCKS, 256, 0, stream>>>(segend, bs);
    k_scan2  <<<1, 256, 0, stream>>>(bs);
    k_scan3  <<<(NBINS + 255) / 256, 256, 0, stream>>>(segend, bs);
    k_scatter<<<(E_EDGES + 255) / 256, 256, 0, stream>>>(src, dst, ety, nrm, segend, es);
    k_layer  <<<NT_BLOCKS, 512, 0, stream>>>(hA, es, segend, wfrag1, lwfrag1, b1, hB);
    k_layer  <<<NT_BLOCKS, 512, 0, stream>>>(hB, es, segend, wfrag2, lwfrag2, b2, hA);
    k_mlp    <<<NPAIRS / 16, 512, 0, stream>>>(hA, drugs, targets, fc1frag, fc1b, fc2W, fc2b, outp);
}

// Round 11
// 269.390 us; speedup vs baseline: 1.5214x; 1.0271x over previous
//
#include <hip/hip_runtime.h>
#include <math.h>

typedef __attribute__((ext_vector_type(8))) short short8;
typedef __attribute__((ext_vector_type(4))) float f32x4;
typedef __attribute__((ext_vector_type(4))) _Float16 half4;
typedef __attribute__((ext_vector_type(8))) _Float16 half8;

#define N_SUBN   20000
#define E_EDGES  400000
#define R_REL    16
#define H_DIM    256
#define NBINS    (N_SUBN * R_REL)          // 320000 (dst,rel) buckets
#define SCAN_CHUNK 2048
#define NSCAN_BLOCKS ((NBINS + SCAN_CHUNK - 1) / SCAN_CHUNK)   // 157
#define NPAIRS   4096
#define TILE_N   32
#define NT_BLOCKS (N_SUBN / TILE_N)                            // 625 exact
#define D2       512
#define ECAP     1024                      // LDS edge-cache capacity (avg ~640/block)

// ---- bf16 hi/lo split helpers (RNE) ----
__device__ __forceinline__ ushort f2bf(float x) {
    uint u = __float_as_uint(x);
    u += 0x7fffu + ((u >> 16) & 1u);
    return (ushort)(u >> 16);
}
__device__ __forceinline__ float bf2f(ushort h) {
    return __uint_as_float(((uint)h) << 16);
}

// ---------------- gather: h0 = fp16(emb[node_ids]) ----------------
__global__ void k_gather(const float* __restrict__ emb, const int* __restrict__ nid,
                         _Float16* __restrict__ h0) {
    int t = blockIdx.x * blockDim.x + threadIdx.x;   // 20000*64 slots of 4 elems
    int node = t >> 6, c = (t & 63) << 2;
    if (node >= N_SUBN) return;
    const float4 s = *reinterpret_cast<const float4*>(emb + (size_t)nid[node] * H_DIM + c);
    half4 d = {(_Float16)s.x, (_Float16)s.y, (_Float16)s.z, (_Float16)s.w};
    *reinterpret_cast<half4*>(h0 + (size_t)node * H_DIM + c) = d;
}

// ---------------- CSR build over bin = dst*R + etype ----------------
__global__ void k_count(const int* __restrict__ dst, const int* __restrict__ ety,
                        int* __restrict__ cnt) {
    int e = blockIdx.x * 256 + threadIdx.x;
    if (e < E_EDGES) atomicAdd(&cnt[dst[e] * R_REL + ety[e]], 1);
}

__global__ void k_scan1(int* __restrict__ data, int* __restrict__ bs) {
    __shared__ int ts[256];
    int base = blockIdx.x * SCAN_CHUNK + threadIdx.x * 8;
    int v[8]; int s = 0;
#pragma unroll
    for (int j = 0; j < 8; j++) {
        int idx = base + j;
        v[j] = (idx < NBINS) ? data[idx] : 0;
        s += v[j];
    }
    ts[threadIdx.x] = s;
    __syncthreads();
    for (int off = 1; off < 256; off <<= 1) {
        int add = (threadIdx.x >= (unsigned)off) ? ts[threadIdx.x - off] : 0;
        __syncthreads();
        ts[threadIdx.x] += add;
        __syncthreads();
    }
    int excl = ts[threadIdx.x] - s;
    if (threadIdx.x == 255) bs[blockIdx.x] = ts[255];
    int run = excl;
#pragma unroll
    for (int j = 0; j < 8; j++) {
        int idx = base + j;
        if (idx < NBINS) data[idx] = run;
        run += v[j];
    }
}

__global__ void k_scan2(int* __restrict__ bs) {
    __shared__ int ls[NSCAN_BLOCKS];
    if (threadIdx.x < NSCAN_BLOCKS) ls[threadIdx.x] = bs[threadIdx.x];
    __syncthreads();
    if (threadIdx.x == 0) {
        int run = 0;
        for (int i = 0; i < NSCAN_BLOCKS; i++) { int t = ls[i]; ls[i] = run; run += t; }
    }
    __syncthreads();
    if (threadIdx.x < NSCAN_BLOCKS) bs[threadIdx.x] = ls[threadIdx.x];
}

__global__ void k_scan3(int* __restrict__ data, const int* __restrict__ bs) {
    int idx = blockIdx.x * 256 + threadIdx.x;
    if (idx < NBINS) data[idx] = data[idx] + bs[idx / SCAN_CHUNK];
}

// scatter increments segend in place: post-scatter segend[bin] = END of bin,
// beg(bin) = (bin==0) ? 0 : segend[bin-1]. Edge packed: (src<<17) | norm_q17.
__global__ void k_scatter(const int* __restrict__ src, const int* __restrict__ dst,
                          const int* __restrict__ ety, const float* __restrict__ nrm,
                          int* __restrict__ segend, uint* __restrict__ es) {
    int e = blockIdx.x * 256 + threadIdx.x;
    if (e >= E_EDGES) return;
    int bin = dst[e] * R_REL + ety[e];
    int pos = atomicAdd(&segend[bin], 1);
    float n = nrm[e];
    uint q = (uint)fminf(n * 131072.f + 0.5f, 131071.f);
    es[pos] = ((uint)src[e] << 17) | q;
}

// ---------------- combined pre-pack + segend zero (one dispatch) ----------------
__device__ __forceinline__ void prep_w_body(const float* __restrict__ w,
                                            ushort* __restrict__ wfrag, int t) {
    int lane = t & 63, f = t >> 6;
    int ot = f & 1, rb = f >> 1;              // rb = r*8+b
    int kbase = (lane >> 4) * 8, n = ot * 16 + (lane & 15);
    ushort hv[8], lv[8];
#pragma unroll
    for (int j = 0; j < 8; j++) {
        float x = w[(size_t)(rb * 32 + kbase + j) * 32 + n];
        ushort h = f2bf(x);
        ushort l = f2bf(x - bf2f(h));
        hv[j] = h; lv[j] = l;
    }
    *reinterpret_cast<short8*>(wfrag + ((size_t)(f * 2 + 0) * 64 + lane) * 8) =
        *reinterpret_cast<short8*>(hv);
    *reinterpret_cast<short8*>(wfrag + ((size_t)(f * 2 + 1) * 64 + lane) * 8) =
        *reinterpret_cast<short8*>(lv);
}

__device__ __forceinline__ void prep_lw_body(const float* __restrict__ lw,
                                             ushort* __restrict__ lwfrag, int t) {
    int lane = t & 63, g = t >> 6;
    int kt = g >> 4, ot = g & 15;
    int kbase = kt * 32 + (lane >> 4) * 8, n = ot * 16 + (lane & 15);
    ushort hv[8], lv[8];
#pragma unroll
    for (int j = 0; j < 8; j++) {
        float x = lw[(size_t)(kbase + j) * H_DIM + n];
        ushort h = f2bf(x);
        ushort l = f2bf(x - bf2f(h));
        hv[j] = h; lv[j] = l;
    }
    *reinterpret_cast<short8*>(lwfrag + ((size_t)(g * 2 + 0) * 64 + lane) * 8) =
        *reinterpret_cast<short8*>(hv);
    *reinterpret_cast<short8*>(lwfrag + ((size_t)(g * 2 + 1) * 64 + lane) * 8) =
        *reinterpret_cast<short8*>(lv);
}

__device__ __forceinline__ void prep_fc1_body(const float* __restrict__ w,
                                              ushort* __restrict__ wfrag, int t) {
    int lane = t & 63, g = t >> 6;
    int kt = g >> 5, ot = g & 31;
    int kbase = kt * 32 + (lane >> 4) * 8, n = ot * 16 + (lane & 15);
    ushort hv[8], lv[8];
#pragma unroll
    for (int j = 0; j < 8; j++) {
        float x = w[(size_t)(kbase + j) * D2 + n];
        ushort h = f2bf(x);
        ushort l = f2bf(x - bf2f(h));
        hv[j] = h; lv[j] = l;
    }
    *reinterpret_cast<short8*>(wfrag + ((size_t)(g * 2 + 0) * 64 + lane) * 8) =
        *reinterpret_cast<short8*>(hv);
    *reinterpret_cast<short8*>(wfrag + ((size_t)(g * 2 + 1) * 64 + lane) * 8) =
        *reinterpret_cast<short8*>(lv);
}

#define ZBLOCKS ((NBINS + 255) / 256)   // 1250

__global__ void k_prep_all(const float* __restrict__ w1, const float* __restrict__ w2,
                           const float* __restrict__ lw1, const float* __restrict__ lw2,
                           const float* __restrict__ fc1W,
                           ushort* __restrict__ wfrag1, ushort* __restrict__ wfrag2,
                           ushort* __restrict__ lwfrag1, ushort* __restrict__ lwfrag2,
                           ushort* __restrict__ fc1frag, int* __restrict__ segend) {
    int b = blockIdx.x, tid = threadIdx.x;
    if (b < 64)        prep_w_body(w1, wfrag1, b * 256 + tid);
    else if (b < 128)  prep_w_body(w2, wfrag2, (b - 64) * 256 + tid);
    else if (b < 160)  prep_lw_body(lw1, lwfrag1, (b - 128) * 256 + tid);
    else if (b < 192)  prep_lw_body(lw2, lwfrag2, (b - 160) * 256 + tid);
    else if (b < 320)  prep_fc1_body(fc1W, fc1frag, (b - 192) * 256 + tid);
    else {
        int i = (b - 320) * 256 + tid;
        if (i < NBINS) segend[i] = 0;
    }
}

// ---------------- fused RGCN-BDD layer (MFMA, bf16 hi/lo 3-term) ----------------
// Round-10 winning structure (TILE 32, 512 thr = 8 waves, 4 interleaved cursors,
// LDS edge cache, single agg buffer, 2 barriers/rel), with h stored in FP16:
// halves the compulsory per-XCD L2 fill traffic (the measured ~1.9 TB/s fabric
// ceiling), converting rows to f32 in registers before exact aggregation.
__global__ __launch_bounds__(512) void k_layer(
    const _Float16* __restrict__ hin, const uint* __restrict__ es,
    const int* __restrict__ segend,
    const ushort* __restrict__ wfrag, const ushort* __restrict__ lwfrag,
    const float* __restrict__ bias, _Float16* __restrict__ hout) {
    __shared__ __align__(16) ushort aggH[TILE_N * H_DIM];
    __shared__ __align__(16) ushort aggLo[TILE_N * H_DIM];
    __shared__ int lofs[TILE_N * R_REL + 1];    // lofs[j]=beg of local bin j; [j+1]=end
    __shared__ uint les[ECAP];                  // block-local edge cache
    char* cH = (char*)aggH;
    char* cL = (char*)aggLo;
    const int n0 = blockIdx.x * TILE_N;
    const int tid = threadIdx.x;
    const int lane = tid & 63, wv = tid >> 6;
    const int col = lane & 15, kg = lane >> 4;
    const short8* wf  = (const short8*)wfrag;
    const short8* lwf = (const short8*)lwfrag;
    const uint laneoff = (uint)(lane << 2);     // element offset (4 fp16 per lane)
    const int t0 = 4 * wv;

    {   // block-local offset table (coalesced, once)
        const int base = n0 * R_REL;
        for (int j = tid; j < TILE_N * R_REL + 1; j += 512) {
            int g = base + j - 1;
            lofs[j] = (g < 0) ? 0 : segend[g];
        }
    }
    __syncthreads();
    const int ebase = lofs[0];
    const int elim  = min(lofs[TILE_N * R_REL] - ebase, ECAP);
    for (int j = tid; j < elim; j += 512) les[j] = es[ebase + j];
    // first loop-top __syncthreads() publishes les

    f32x4 acc[2][2];
#pragma unroll
    for (int mt = 0; mt < 2; ++mt)
#pragma unroll
        for (int ot = 0; ot < 2; ++ot) acc[mt][ot] = (f32x4){0.f, 0.f, 0.f, 0.f};

    for (int r = 0; r < R_REL; ++r) {
        __syncthreads();   // les/lofs ready (r=0) / previous MFMA reads done
        // ---- 4-way interleaved aggregation of nodes t0..t0+3 ----
        int e0 = lofs[(t0 + 0) * R_REL + r], d0 = lofs[(t0 + 0) * R_REL + r + 1];
        int e1 = lofs[(t0 + 1) * R_REL + r], d1 = lofs[(t0 + 1) * R_REL + r + 1];
        int e2 = lofs[(t0 + 2) * R_REL + r], d2 = lofs[(t0 + 2) * R_REL + r + 1];
        int e3 = lofs[(t0 + 3) * R_REL + r], d3 = lofs[(t0 + 3) * R_REL + r + 1];
        float4 a0 = make_float4(0.f, 0.f, 0.f, 0.f);
        float4 a1 = make_float4(0.f, 0.f, 0.f, 0.f);
        float4 a2 = make_float4(0.f, 0.f, 0.f, 0.f);
        float4 a3 = make_float4(0.f, 0.f, 0.f, 0.f);
        while ((e0 < d0) | (e1 < d1) | (e2 < d2) | (e3 < d3)) {
            bool g0 = e0 < d0, g1 = e1 < d1, g2 = e2 < d2, g3 = e3 < d3;
            uint p0 = 0, p1 = 0, p2 = 0, p3 = 0;
            if (g0) { int i = e0 - ebase; p0 = (i < ECAP) ? les[i] : es[e0]; ++e0; }
            if (g1) { int i = e1 - ebase; p1 = (i < ECAP) ? les[i] : es[e1]; ++e1; }
            if (g2) { int i = e2 - ebase; p2 = (i < ECAP) ? les[i] : es[e2]; ++e2; }
            if (g3) { int i = e3 - ebase; p3 = (i < ECAP) ? les[i] : es[e3]; ++e3; }
            if (g0) {
                const half4 x = *reinterpret_cast<const half4*>(
                    hin + (size_t)(p0 >> 17) * H_DIM + laneoff);
                float nm = (float)(p0 & 0x1FFFFu) * (1.f / 131072.f);
                a0.x = fmaf((float)x[0], nm, a0.x); a0.y = fmaf((float)x[1], nm, a0.y);
                a0.z = fmaf((float)x[2], nm, a0.z); a0.w = fmaf((float)x[3], nm, a0.w);
            }
            if (g1) {
                const half4 x = *reinterpret_cast<const half4*>(
                    hin + (size_t)(p1 >> 17) * H_DIM + laneoff);
                float nm = (float)(p1 & 0x1FFFFu) * (1.f / 131072.f);
                a1.x = fmaf((float)x[0], nm, a1.x); a1.y = fmaf((float)x[1], nm, a1.y);
                a1.z = fmaf((float)x[2], nm, a1.z); a1.w = fmaf((float)x[3], nm, a1.w);
            }
            if (g2) {
                const half4 x = *reinterpret_cast<const half4*>(
                    hin + (size_t)(p2 >> 17) * H_DIM + laneoff);
                float nm = (float)(p2 & 0x1FFFFu) * (1.f / 131072.f);
                a2.x = fmaf((float)x[0], nm, a2.x); a2.y = fmaf((float)x[1], nm, a2.y);
                a2.z = fmaf((float)x[2], nm, a2.z); a2.w = fmaf((float)x[3], nm, a2.w);
            }
            if (g3) {
                const half4 x = *reinterpret_cast<const half4*>(
                    hin + (size_t)(p3 >> 17) * H_DIM + laneoff);
                float nm = (float)(p3 & 0x1FFFFu) * (1.f / 131072.f);
                a3.x = fmaf((float)x[0], nm, a3.x); a3.y = fmaf((float)x[1], nm, a3.y);
                a3.z = fmaf((float)x[2], nm, a3.z); a3.w = fmaf((float)x[3], nm, a3.w);
            }
        }
#pragma unroll
        for (int i = 0; i < 4; ++i) {
            float4 av = (i == 0) ? a0 : (i == 1) ? a1 : (i == 2) ? a2 : a3;
            int t = t0 + i;
            ushort h0 = f2bf(av.x), h1 = f2bf(av.y), h2 = f2bf(av.z), h3 = f2bf(av.w);
            uint2 ph = make_uint2((uint)h0 | ((uint)h1 << 16), (uint)h2 | ((uint)h3 << 16));
            uint2 pl = make_uint2(
                (uint)f2bf(av.x - bf2f(h0)) | ((uint)f2bf(av.y - bf2f(h1)) << 16),
                (uint)f2bf(av.z - bf2f(h2)) | ((uint)f2bf(av.w - bf2f(h3)) << 16));
            uint byte = (uint)(t * 512) + ((((lane >> 1) ^ (t & 7)) << 4) | ((lane & 1) << 3));
            *(uint2*)(cH + byte) = ph;
            *(uint2*)(cL + byte) = pl;
        }
        __syncthreads();
        // ---- transform: wave wv owns b-block wv ----
#pragma unroll
        for (int ot = 0; ot < 2; ++ot) {
            int f = (r * 8 + wv) * 2 + ot;
            short8 Bh = wf[(f * 2 + 0) * 64 + lane];
            short8 Bl = wf[(f * 2 + 1) * 64 + lane];
#pragma unroll
            for (int mt = 0; mt < 2; ++mt) {
                int row = mt * 16 + col;
                uint ab = (uint)(row * 512) + ((uint)((wv * 4 + kg) ^ (row & 7)) << 4);
                short8 Ah = *(const short8*)(cH + ab);
                short8 Al = *(const short8*)(cL + ab);
                f32x4 a = acc[mt][ot];
                a = __builtin_amdgcn_mfma_f32_16x16x32_bf16(Ah, Bh, a, 0, 0, 0);
                a = __builtin_amdgcn_mfma_f32_16x16x32_bf16(Ah, Bl, a, 0, 0, 0);
                a = __builtin_amdgcn_mfma_f32_16x16x32_bf16(Al, Bh, a, 0, 0, 0);
                acc[mt][ot] = a;
            }
        }
    }

    // ---- self-loop: restage h tile as hi/lo, K=256 MFMA sweep ----
    __syncthreads();
#pragma unroll
    for (int i = 0; i < 4; ++i) {
        int t = t0 + i;
        const half4 xh = *reinterpret_cast<const half4*>(
            hin + (size_t)(n0 + t) * H_DIM + laneoff);
        float4 xv = make_float4((float)xh[0], (float)xh[1], (float)xh[2], (float)xh[3]);
        ushort h0 = f2bf(xv.x), h1 = f2bf(xv.y), h2 = f2bf(xv.z), h3 = f2bf(xv.w);
        uint2 ph = make_uint2((uint)h0 | ((uint)h1 << 16), (uint)h2 | ((uint)h3 << 16));
        uint2 pl = make_uint2(
            (uint)f2bf(xv.x - bf2f(h0)) | ((uint)f2bf(xv.y - bf2f(h1)) << 16),
            (uint)f2bf(xv.z - bf2f(h2)) | ((uint)f2bf(xv.w - bf2f(h3)) << 16));
        uint byte = (uint)(t * 512) + ((((lane >> 1) ^ (t & 7)) << 4) | ((lane & 1) << 3));
        *(uint2*)(cH + byte) = ph;
        *(uint2*)(cL + byte) = pl;
    }
    __syncthreads();
#pragma unroll
    for (int kt = 0; kt < 8; ++kt) {
#pragma unroll
        for (int ot = 0; ot < 2; ++ot) {
            int g = kt * 16 + 2 * wv + ot;
            short8 Bh = lwf[(g * 2 + 0) * 64 + lane];
            short8 Bl = lwf[(g * 2 + 1) * 64 + lane];
#pragma unroll
            for (int mt = 0; mt < 2; ++mt) {
                int row = mt * 16 + col;
                uint ab = (uint)(row * 512) + ((uint)((kt * 4 + kg) ^ (row & 7)) << 4);
                short8 Ah = *(const short8*)(cH + ab);
                short8 Al = *(const short8*)(cL + ab);
                f32x4 a = acc[mt][ot];
                a = __builtin_amdgcn_mfma_f32_16x16x32_bf16(Ah, Bh, a, 0, 0, 0);
                a = __builtin_amdgcn_mfma_f32_16x16x32_bf16(Ah, Bl, a, 0, 0, 0);
                a = __builtin_amdgcn_mfma_f32_16x16x32_bf16(Al, Bh, a, 0, 0, 0);
                acc[mt][ot] = a;
            }
        }
    }

    // ---- epilogue: C/D layout col=lane&15, row=(lane>>4)*4+reg; fp16 store ----
#pragma unroll
    for (int mt = 0; mt < 2; ++mt) {
        int nbase = n0 + mt * 16 + kg * 4;
#pragma unroll
        for (int ot = 0; ot < 2; ++ot) {
            int o = 32 * wv + ot * 16 + col;
            float bo = bias[o];
#pragma unroll
            for (int rg = 0; rg < 4; ++rg)
                hout[(size_t)(nbase + rg) * H_DIM + o] = (_Float16)(acc[mt][ot][rg] + bo);
        }
    }
}

// ---------------- fused concat + fc1(MFMA) + relu + fc2 + sigmoid ----------------
__global__ __launch_bounds__(512) void k_mlp(
    const _Float16* __restrict__ h, const int* __restrict__ drugs,
    const int* __restrict__ targets,
    const ushort* __restrict__ fc1frag, const float* __restrict__ b1f,
    const float* __restrict__ W2, const float* __restrict__ b2f,
    float* __restrict__ outp) {
    __shared__ __align__(16) ushort xH[16 * D2];
    __shared__ __align__(16) ushort xL[16 * D2];
    __shared__ float red[16][8];
    char* cH = (char*)xH;
    char* cL = (char*)xL;
    const int tid = threadIdx.x;
    const int lane = tid & 63, wv = tid >> 6;
    const int col = lane & 15, kg = lane >> 4;
    const int p0 = blockIdx.x * 16;
    const short8* wf = (const short8*)fc1frag;

    {   // stage X = [h[drug] | h[target]] (fp16) as bf16 hi/lo, swizzled
        int p = tid >> 5;
        int cc = (tid & 31) * 16;
        int di = drugs[p0 + p], ti = targets[p0 + p];
        const _Float16* srcp = (cc < H_DIM) ? (h + (size_t)di * H_DIM + cc)
                                            : (h + (size_t)ti * H_DIM + (cc - H_DIM));
#pragma unroll
        for (int j = 0; j < 2; ++j) {
            half8 v = *reinterpret_cast<const half8*>(srcp + j * 8);
            float f[8];
#pragma unroll
            for (int q = 0; q < 8; ++q) f[q] = (float)v[q];
            short8 hv, lv;
#pragma unroll
            for (int q = 0; q < 8; ++q) {
                ushort hh = f2bf(f[q]);
                hv[q] = (short)hh;
                lv[q] = (short)f2bf(f[q] - bf2f(hh));
            }
            uint chunk = (uint)((tid & 31) * 2 + j);
            uint byte = (uint)p * 1024 + ((chunk ^ (uint)(p & 7)) << 4);
            *(short8*)(cH + byte) = hv;
            *(short8*)(cL + byte) = lv;
        }
    }
    __syncthreads();

    f32x4 acc[4];
#pragma unroll
    for (int oi = 0; oi < 4; ++oi) acc[oi] = (f32x4){0.f, 0.f, 0.f, 0.f};

    for (int kt = 0; kt < 16; ++kt) {
        uint ab = (uint)col * 1024 + ((uint)((kt * 4 + kg) ^ (col & 7)) << 4);
        short8 Ah = *(const short8*)(cH + ab);
        short8 Al = *(const short8*)(cL + ab);
#pragma unroll
        for (int oi = 0; oi < 4; ++oi) {
            int g = kt * 32 + wv * 4 + oi;
            short8 Bh = wf[(g * 2 + 0) * 64 + lane];
            short8 Bl = wf[(g * 2 + 1) * 64 + lane];
            f32x4 a = acc[oi];
            a = __builtin_amdgcn_mfma_f32_16x16x32_bf16(Ah, Bh, a, 0, 0, 0);
            a = __builtin_amdgcn_mfma_f32_16x16x32_bf16(Ah, Bl, a, 0, 0, 0);
            a = __builtin_amdgcn_mfma_f32_16x16x32_bf16(Al, Bh, a, 0, 0, 0);
            a = __builtin_amdgcn_mfma_f32_16x16x32_bf16(Al, Bl, a, 0, 0, 0);
            acc[oi] = a;
        }
    }

    float val[4] = {0.f, 0.f, 0.f, 0.f};
#pragma unroll
    for (int oi = 0; oi < 4; ++oi) {
        int o = 64 * wv + oi * 16 + col;
        float b1o = b1f[o], w2o = W2[o];
#pragma unroll
        for (int rg = 0; rg < 4; ++rg) {
            float y = acc[oi][rg] + b1o;
            y = y > 0.f ? y : 0.f;
            val[rg] = fmaf(y, w2o, val[rg]);
        }
    }
#pragma unroll
    for (int rg = 0; rg < 4; ++rg) {
        float v = val[rg];
        v += __shfl_xor(v, 1, 64);
        v += __shfl_xor(v, 2, 64);
        v += __shfl_xor(v, 4, 64);
        v += __shfl_xor(v, 8, 64);
        val[rg] = v;
    }
    if (col == 0) {
#pragma unroll
        for (int rg = 0; rg < 4; ++rg) red[kg * 4 + rg][wv] = val[rg];
    }
    __syncthreads();
    if (tid < 16) {
        float s = 0.f;
#pragma unroll
        for (int w = 0; w < 8; w++) s += red[tid][w];
        s += b2f[0];
        outp[p0 + tid] = 1.f / (1.f + __expf(-s));
    }
}

extern "C" void kernel_launch(void* const* d_in, const int* in_sizes, int n_in,
                              void* d_out, int out_size, void* d_ws, size_t ws_size,
                              hipStream_t stream) {
    (void)in_sizes; (void)n_in; (void)out_size; (void)ws_size;
    const int*   drugs   = (const int*)d_in[0];
    const int*   targets = (const int*)d_in[1];
    const int*   nid     = (const int*)d_in[2];
    const int*   src     = (const int*)d_in[3];
    const int*   dst     = (const int*)d_in[4];
    const int*   ety     = (const int*)d_in[5];
    const float* nrm     = (const float*)d_in[6];
    const float* emb     = (const float*)d_in[7];
    const float* w1      = (const float*)d_in[8];
    const float* lw1     = (const float*)d_in[9];
    const float* b1      = (const float*)d_in[10];
    const float* w2      = (const float*)d_in[11];
    const float* lw2     = (const float*)d_in[12];
    const float* b2      = (const float*)d_in[13];
    const float* fc1W    = (const float*)d_in[14];
    const float* fc1b    = (const float*)d_in[15];
    const float* fc2W    = (const float*)d_in[16];
    const float* fc2b    = (const float*)d_in[17];
    float* outp = (float*)d_out;

    // ws layout — same offsets as round-10 (h arrays now fp16, smaller than slots).
    char* ws = (char*)d_ws;
    ushort*   wfrag1  = (ushort*)  (ws);                 //    524,288
    ushort*   wfrag2  = (ushort*)  (ws + 524288);        //    524,288
    ushort*   lwfrag1 = (ushort*)  (ws + 1048576);       //    262,144
    ushort*   lwfrag2 = (ushort*)  (ws + 1310720);       //    262,144
    ushort*   fc1frag = (ushort*)  (ws + 1572864);       //  1,048,576
    _Float16* hA      = (_Float16*)(ws + 2621440);       // 10,240,000 used
    _Float16* hB      = (_Float16*)(ws + 23101440);      // 10,240,000 used
    int*      segend  = (int*)     (ws + 43581440);      //  1,280,000
    int*      bs      = (int*)     (ws + 44861440);      //      1,024
    uint*     es      = (uint*)    (ws + 44862464);      //  1,600,000 -> end 46,462,464

    k_prep_all<<<320 + ZBLOCKS, 256, 0, stream>>>(w1, w2, lw1, lw2, fc1W,
                                                  wfrag1, wfrag2, lwfrag1, lwfrag2,
                                                  fc1frag, segend);
    k_gather <<<5000, 256, 0, stream>>>(emb, nid, hA);
    k_count  <<<(E_EDGES + 255) / 256, 256, 0, stream>>>(dst, ety, segend);
    k_scan1  <<<NSCAN_BLOCKS, 256, 0, stream>>>(segend, bs);
    k_scan2  <<<1, 256, 0, stream>>>(bs);
    k_scan3  <<<(NBINS + 255) / 256, 256, 0, stream>>>(segend, bs);
    k_scatter<<<(E_EDGES + 255) / 256, 256, 0, stream>>>(src, dst, ety, nrm, segend, es);
    k_layer  <<<NT_BLOCKS, 512, 0, stream>>>(hA, es, segend, wfrag1, lwfrag1, b1, hB);
    k_layer  <<<NT_BLOCKS, 512, 0, stream>>>(hB, es, segend, wfrag2, lwfrag2, b2, hA);
    k_mlp    <<<NPAIRS / 16, 512, 0, stream>>>(hA, drugs, targets, fc1frag, fc1b, fc2W, fc2b, outp);
}